// Round 2
// baseline (489.442 us; speedup 1.0000x reference)
//
#include <hip/hip_runtime.h>

typedef unsigned long long u64;

#define NROWS 2048
#define MROWS 4096
#define BLAB  1024
#define HEADS 8

// ---------- shared tile helpers (64 rows x 64 floats) ----------

// coalesced global load: thread covers 4 float4s; wave covers 4 contiguous rows
__device__ __forceinline__ void load_tile(const float* __restrict__ src, int tid, float4 r[4]) {
  const int ty = tid >> 4, tx = tid & 15;
#pragma unroll
  for (int k = 0; k < 4; ++k)
    r[k] = *(const float4*)(src + (k * 16 + ty) * 64 + tx * 4);
}

// B layout: 16 groups of 4 rows, group stride 260 floats (4-float pad per group)
// -> read B[4*ty+rj][f4*4..+3] is conflict-free (banks b, b+4, b+8, b+12 across ty)
__device__ __forceinline__ void store_rowg(float* __restrict__ Bl, int tid, const float4 r[4]) {
  const int ty = tid >> 4, tx = tid & 15;
#pragma unroll
  for (int k = 0; k < 4; ++k) {
    const int row = k * 16 + ty;
    *(float4*)(Bl + (row >> 2) * 260 + (row & 3) * 64 + tx * 4) = r[k];
  }
}

// A^T layout with XOR swizzle: At[f*64 + (i ^ ((f>>2 & 7)<<2))]
// -> both the scalar transpose writes and the float4 reads are ~2-way (free)
__device__ __forceinline__ void store_swzT(float* __restrict__ At, int tid, const float4 r[4]) {
  const int ty = tid >> 4, ch = tid & 15;
  const int e = (ch & 7) << 2;
#pragma unroll
  for (int k = 0; k < 4; ++k) {
    const int row = k * 16 + ty;
    const int cs = row ^ e;
    At[(4 * ch + 0) * 64 + cs] = r[k].x;
    At[(4 * ch + 1) * 64 + cs] = r[k].y;
    At[(4 * ch + 2) * 64 + cs] = r[k].z;
    At[(4 * ch + 3) * 64 + cs] = r[k].w;
  }
}

// 64x64 fp32 tile product: c[ri][rj] = sum_f A[4tx+ri][f] * B[4ty+rj][f]
__device__ __forceinline__ void mm_tile(const float* __restrict__ At, const float* __restrict__ Bl,
                                        int tx, int ty, float c[4][4]) {
#pragma unroll
  for (int f4 = 0; f4 < 16; ++f4) {
    const int ac = (4 * tx) ^ ((f4 & 7) << 2);
    float a[4][4], b[4][4];
#pragma unroll
    for (int q = 0; q < 4; ++q) {
      float4 t = *(const float4*)(At + (4 * f4 + q) * 64 + ac);
      a[q][0] = t.x; a[q][1] = t.y; a[q][2] = t.z; a[q][3] = t.w;
    }
#pragma unroll
    for (int rj = 0; rj < 4; ++rj) {
      float4 t = *(const float4*)(Bl + ty * 260 + rj * 64 + 4 * f4);
      b[rj][0] = t.x; b[rj][1] = t.y; b[rj][2] = t.z; b[rj][3] = t.w;
    }
#pragma unroll
    for (int ri = 0; ri < 4; ++ri)
#pragma unroll
      for (int rj = 0; rj < 4; ++rj)
        c[ri][rj] += a[0][ri] * b[rj][0] + a[1][ri] * b[rj][1]
                   + a[2][ri] * b[rj][2] + a[3][ri] * b[rj][3];
  }
}

// combine per-thread (m,S) partials over the ty dimension, store one (m,S) per row
__device__ __forceinline__ void reduce_store_ms(const float mm_[4], const float ss_[4],
                                                float* __restrict__ red, int tid, int ibase,
                                                float* __restrict__ gm, float* __restrict__ gs,
                                                int off) {
  const int w = tid >> 6;
#pragma unroll
  for (int ri = 0; ri < 4; ++ri) {
    float m = mm_[ri], s = ss_[ri];
#pragma unroll
    for (int d = 16; d <= 32; d <<= 1) {
      float mo = __shfl_xor(m, d, 64);
      float so = __shfl_xor(s, d, 64);
      float mn = fmaxf(m, mo);
      s = s * __expf(m - mn) + so * __expf(mo - mn);
      m = mn;
    }
    if ((tid & 63) < 16) {
      const int il = 4 * (tid & 15) + ri;
      red[(w * 64 + il) * 2]     = m;
      red[(w * 64 + il) * 2 + 1] = s;
    }
  }
  __syncthreads();
  if (tid < 64) {
    float m = red[tid * 2], s = red[tid * 2 + 1];
#pragma unroll
    for (int w2 = 1; w2 < 4; ++w2) {
      float mo = red[(w2 * 64 + tid) * 2], so = red[(w2 * 64 + tid) * 2 + 1];
      float mn = fmaxf(m, mo);
      s = s * __expf(m - mn) + so * __expf(mo - mn);
      m = mn;
    }
    gm[(ibase + tid) * 32 + off] = m;
    gs[(ibase + tid) * 32 + off] = s;
  }
  __syncthreads();
}

// ---------- kernels ----------

// label bitmasks (one wave per label row) + zero the accumulation buffers
__global__ void k_setup(const float* __restrict__ labels, u64* __restrict__ lbits,
                        float* __restrict__ zbuf) {
  const int gtid = blockIdx.x * blockDim.x + threadIdx.x;
  if (gtid < 4096) zbuf[gtid] = 0.0f;  // rowsum(2048) + rowcnt(2048)
  const int wid = gtid >> 6;
  const int lane = threadIdx.x & 63;
  if (wid < BLAB) {
    float v = labels[wid * 64 + lane];
    u64 msk = __ballot(v != 0.0f);
    if (lane == 0) lbits[wid] = msk;
  }
}

// L2-normalize per (row, head); output layouts (H, N, 64) and (H, M, 64)
__global__ void k_norm(const float* __restrict__ feat, const float* __restrict__ negs,
                       float* __restrict__ fn, float* __restrict__ nn) {
  const int wid  = (blockIdx.x * blockDim.x + threadIdx.x) >> 6;
  const int lane = threadIdx.x & 63;
  float v;
  float* dst;
  if (wid < NROWS * HEADS) {
    const int i = wid >> 3, h = wid & 7;
    const int b = i & (BLAB - 1), vv = i >> 10;          // i = vv*B + b
    v = feat[(b * 2 + vv) * 512 + h * 64 + lane];
    dst = fn + (h * NROWS + i) * 64 + lane;
  } else {
    const int wid2 = wid - NROWS * HEADS;
    const int m = wid2 >> 3, h = wid2 & 7;
    const int b2 = m & (2048 - 1), vv = m >> 11;         // m = vv*B2 + b2
    v = negs[(b2 * 2 + vv) * 512 + h * 64 + lane];
    dst = nn + (h * MROWS + m) * 64 + lane;
  }
  float ss = v * v;
#pragma unroll
  for (int d = 32; d; d >>= 1) ss += __shfl_xor(ss, d, 64);
  const float inv = 1.0f / fmaxf(sqrtf(ss), 1e-12f);
  *dst = v * inv;
}

// pass A: online (max, sum-exp) over j (D, self excluded from sum) and over m (DN)
// grid: 1024 = head(8) x i-tile(32) x j-split(4)
__global__ __launch_bounds__(256) void k_passA(const float* __restrict__ fn,
                                               const float* __restrict__ nn,
                                               float* __restrict__ m1p, float* __restrict__ S1p,
                                               float* __restrict__ m2p, float* __restrict__ S2p) {
  __shared__ __align__(16) float At[64 * 64];
  __shared__ __align__(16) float Bl[16 * 260];
  __shared__ float red[512];
  const int tid  = threadIdx.x;
  const int head = blockIdx.x & 7;
  const int it   = (blockIdx.x >> 3) & 31;
  const int js   = blockIdx.x >> 8;
  const int ibase = it * 64;
  const int tx = tid & 15, ty = tid >> 4;
  const float invT = 1.0f / 0.07f;
  const float* fh = fn + head * (NROWS * 64);
  const float* nh = nn + head * (MROWS * 64);
  {
    float4 rA[4];
    load_tile(fh + ibase * 64, tid, rA);
    store_swzT(At, tid, rA);
  }
  float4 rg[4];
  const int jt0 = js * 8,  jt1 = jt0 + 8;
  const int mt0 = js * 16, mt1 = mt0 + 16;
  load_tile(fh + jt0 * 4096, tid, rg);
  float mm_[4], ss_[4];
#pragma unroll
  for (int r = 0; r < 4; ++r) { mm_[r] = -3.0e38f; ss_[r] = 0.0f; }

  for (int jt = jt0; jt < jt1; ++jt) {
    __syncthreads();
    store_rowg(Bl, tid, rg);
    if (jt + 1 < jt1) load_tile(fh + (jt + 1) * 4096, tid, rg);
    else              load_tile(nh + mt0 * 4096, tid, rg);
    __syncthreads();
    float c[4][4] = {};
    mm_tile(At, Bl, tx, ty, c);
    const int jb = jt * 64 + 4 * ty;
#pragma unroll
    for (int ri = 0; ri < 4; ++ri) {
      const int gi = ibase + 4 * tx + ri;
#pragma unroll
      for (int rj = 0; rj < 4; ++rj) {
        const float x  = c[ri][rj] * invT;
        const float mn = fmaxf(mm_[ri], x);
        const float add = (gi == jb + rj) ? 0.0f : __expf(x - mn);
        ss_[ri] = ss_[ri] * __expf(mm_[ri] - mn) + add;
        mm_[ri] = mn;
      }
    }
  }
  reduce_store_ms(mm_, ss_, red, tid, ibase, m1p, S1p, head * 4 + js);

#pragma unroll
  for (int r = 0; r < 4; ++r) { mm_[r] = -3.0e38f; ss_[r] = 0.0f; }
  for (int mt = mt0; mt < mt1; ++mt) {
    __syncthreads();
    store_rowg(Bl, tid, rg);
    if (mt + 1 < mt1) load_tile(nh + (mt + 1) * 4096, tid, rg);
    __syncthreads();
    float c[4][4] = {};
    mm_tile(At, Bl, tx, ty, c);
#pragma unroll
    for (int ri = 0; ri < 4; ++ri) {
#pragma unroll
      for (int rj = 0; rj < 4; ++rj) {
        const float x  = c[ri][rj] * invT;
        const float mn = fmaxf(mm_[ri], x);
        ss_[ri] = ss_[ri] * __expf(mm_[ri] - mn) + __expf(x - mn);
        mm_[ri] = mn;
      }
    }
  }
  reduce_store_ms(mm_, ss_, red, tid, ibase, m2p, S2p, head * 4 + js);
}

// pass B: per (i,j) max/argmax over heads, masked accumulation of log_prob
// grid: 1024 = i-tile(32) x j-tile(32)
__global__ __launch_bounds__(256) void k_passB(const float* __restrict__ fn,
                                               const float* __restrict__ m1p, const float* __restrict__ S1p,
                                               const float* __restrict__ m2p, const float* __restrict__ S2p,
                                               const u64* __restrict__ lbits,
                                               float* __restrict__ rowsum, float* __restrict__ rowcnt) {
  __shared__ __align__(16) float At[64 * 64];
  __shared__ __align__(16) float Bl[16 * 260];
  __shared__ float dn[512];
  __shared__ float red[512];
  const int tid = threadIdx.x;
  const int it = blockIdx.x >> 5, jt = blockIdx.x & 31;
  const int ibase = it * 64, jbase = jt * 64;
  const int tx = tid & 15, ty = tid >> 4;
  const float invT = 1.0f / 0.07f;

  // merge the 4 j-split partials and build denom[i_local][h]
  for (int e = tid; e < 512; e += 256) {
    const int il = e >> 3, h = e & 7;
    const int base = (ibase + il) * 32 + h * 4;
    float m = -3.0e38f, s = 0.0f;
#pragma unroll
    for (int q = 0; q < 4; ++q) {
      float mo = m1p[base + q], so = S1p[base + q];
      float mn = fmaxf(m, mo);
      s = s * __expf(m - mn) + so * __expf(mo - mn);
      m = mn;
    }
    float m2 = -3.0e38f, s2 = 0.0f;
#pragma unroll
    for (int q = 0; q < 4; ++q) {
      float mo = m2p[base + q], so = S2p[base + q];
      float mn = fmaxf(m2, mo);
      s2 = s2 * __expf(m2 - mn) + so * __expf(mo - mn);
      m2 = mn;
    }
    dn[e] = m + __logf(s + s2);
  }

  float4 rA[4], rB[4];
  load_tile(fn + ibase * 64, tid, rA);
  load_tile(fn + jbase * 64, tid, rB);
  float maxd[4][4];
  int besth[4][4];
#pragma unroll
  for (int ri = 0; ri < 4; ++ri)
#pragma unroll
    for (int rj = 0; rj < 4; ++rj) { maxd[ri][rj] = -3.0e38f; besth[ri][rj] = 0; }

  for (int h = 0; h < 8; ++h) {
    __syncthreads();
    store_swzT(At, tid, rA);
    store_rowg(Bl, tid, rB);
    if (h < 7) {
      load_tile(fn + ((h + 1) * NROWS + ibase) * 64, tid, rA);
      load_tile(fn + ((h + 1) * NROWS + jbase) * 64, tid, rB);
    }
    __syncthreads();
    float c[4][4] = {};
    mm_tile(At, Bl, tx, ty, c);
#pragma unroll
    for (int ri = 0; ri < 4; ++ri)
#pragma unroll
      for (int rj = 0; rj < 4; ++rj)
        if (c[ri][rj] > maxd[ri][rj]) { maxd[ri][rj] = c[ri][rj]; besth[ri][rj] = h; }
  }

  u64 lbi[4];
#pragma unroll
  for (int ri = 0; ri < 4; ++ri) lbi[ri] = lbits[(ibase + 4 * tx + ri) & (BLAB - 1)];
  float rs[4] = {0, 0, 0, 0}, rc[4] = {0, 0, 0, 0};
#pragma unroll
  for (int ri = 0; ri < 4; ++ri) {
    const int gi = ibase + 4 * tx + ri;
#pragma unroll
    for (int rj = 0; rj < 4; ++rj) {
      const int gj = jbase + 4 * ty + rj;
      const u64 lbj = lbits[gj & (BLAB - 1)];
      if (gi != gj && (lbi[ri] & lbj)) {
        rs[ri] += maxd[ri][rj] * invT - dn[(4 * tx + ri) * 8 + besth[ri][rj]];
        rc[ri] += 1.0f;
      }
    }
  }

  const int w = tid >> 6;
#pragma unroll
  for (int ri = 0; ri < 4; ++ri) {
    float s = rs[ri], cc = rc[ri];
    s += __shfl_xor(s, 16, 64); cc += __shfl_xor(cc, 16, 64);
    s += __shfl_xor(s, 32, 64); cc += __shfl_xor(cc, 32, 64);
    if ((tid & 63) < 16) {
      const int il = 4 * (tid & 15) + ri;
      red[(w * 64 + il) * 2]     = s;
      red[(w * 64 + il) * 2 + 1] = cc;
    }
  }
  __syncthreads();
  if (tid < 64) {
    float s = 0.0f, cc = 0.0f;
#pragma unroll
    for (int w2 = 0; w2 < 4; ++w2) {
      s  += red[(w2 * 64 + tid) * 2];
      cc += red[(w2 * 64 + tid) * 2 + 1];
    }
    atomicAdd(&rowsum[ibase + tid], s);
    atomicAdd(&rowcnt[ibase + tid], cc);
  }
}

// final: mean over rows with cnt>0 of -(rowsum/cnt); NaN -> 0
__global__ void k_final(const float* __restrict__ rowsum, const float* __restrict__ rowcnt,
                        float* __restrict__ out) {
  __shared__ float sdata[4][2];
  const int tid = threadIdx.x;
  float s = 0.0f, c = 0.0f;
  for (int i = tid; i < NROWS; i += 256) {
    const float cnt = rowcnt[i];
    if (cnt > 0.0f) { s -= rowsum[i] / cnt; c += 1.0f; }
  }
#pragma unroll
  for (int d = 32; d; d >>= 1) { s += __shfl_xor(s, d, 64); c += __shfl_xor(c, d, 64); }
  const int w = tid >> 6;
  if ((tid & 63) == 0) { sdata[w][0] = s; sdata[w][1] = c; }
  __syncthreads();
  if (tid == 0) {
    s = 0.0f; c = 0.0f;
#pragma unroll
    for (int w2 = 0; w2 < 4; ++w2) { s += sdata[w2][0]; c += sdata[w2][1]; }
    out[0] = (c > 0.0f) ? s / c : 0.0f;
  }
}

extern "C" void kernel_launch(void* const* d_in, const int* in_sizes, int n_in,
                              void* d_out, int out_size, void* d_ws, size_t ws_size,
                              hipStream_t stream) {
  const float* feat   = (const float*)d_in[0];
  const float* negs   = (const float*)d_in[1];
  const float* labels = (const float*)d_in[2];
  float* out = (float*)d_out;

  float* fn  = (float*)d_ws;                 // (H, N, 64)  = 1,048,576 floats
  float* nn  = fn  + 8 * NROWS * 64;         // (H, M, 64)  = 2,097,152 floats
  float* m1p = nn  + 8 * MROWS * 64;         // (N, H, 4)   = 65,536
  float* S1p = m1p + 65536;
  float* m2p = S1p + 65536;
  float* S2p = m2p + 65536;
  float* rowsum = S2p + 65536;               // 2048
  float* rowcnt = rowsum + 2048;             // 2048
  u64*   lbits  = (u64*)(rowcnt + 2048);     // 1024 u64

  k_setup<<<256, 256, 0, stream>>>(labels, lbits, rowsum);
  k_norm<<<12288, 256, 0, stream>>>(feat, negs, fn, nn);
  k_passA<<<1024, 256, 0, stream>>>(fn, nn, m1p, S1p, m2p, S2p);
  k_passB<<<1024, 256, 0, stream>>>(fn, m1p, S1p, m2p, S2p, lbits, rowsum, rowcnt);
  k_final<<<1, 256, 0, stream>>>(rowsum, rowcnt, out);
}

// Round 3
// 225.663 us; speedup vs baseline: 2.1689x; 2.1689x over previous
//
#include <hip/hip_runtime.h>

typedef unsigned long long u64;
typedef unsigned short ushort_t;
typedef __bf16 bf16x8 __attribute__((ext_vector_type(8)));
typedef float f32x4 __attribute__((ext_vector_type(4)));

#define NROWS 2048
#define MROWS 4096
#define BLAB  1024
#define INVT  (1.0f / 0.07f)

__device__ __forceinline__ bf16x8 ldb(const ushort_t* p) {
  return __builtin_bit_cast(bf16x8, *(const uint4*)p);
}

__device__ __forceinline__ ushort_t f2bf(float f) {
  unsigned u = __float_as_uint(f);
  u += 0x7fff + ((u >> 16) & 1);   // RNE (inputs are finite)
  return (ushort_t)(u >> 16);
}

// ---------- kernels ----------

// label bitmasks (one wave per label row) + zero rowsum/rowcnt
__global__ void k_setup(const float* __restrict__ labels, u64* __restrict__ lbits,
                        float* __restrict__ zbuf) {
  const int gtid = blockIdx.x * blockDim.x + threadIdx.x;
  if (gtid < 4096) zbuf[gtid] = 0.0f;
  const int wid  = gtid >> 6;
  const int lane = threadIdx.x & 63;
  if (wid < BLAB) {
    float v = labels[wid * 64 + lane];
    u64 msk = __ballot(v != 0.0f);
    if (lane == 0) lbits[wid] = msk;
  }
}

// L2-normalize per (row, head), emit bf16; layouts (H,N,64) and (H,M,64)
// one 16-lane group per (row,head) pair; lane covers 4 floats
__global__ void k_norm(const float* __restrict__ feat, const float* __restrict__ negs,
                       ushort_t* __restrict__ fnb, ushort_t* __restrict__ nnb) {
  const int wid  = (blockIdx.x * blockDim.x + threadIdx.x) >> 6;
  const int lane = threadIdx.x & 63;
  const int g = lane >> 4, ln = lane & 15;
  const int p = wid * 4 + g;                    // pair index
  const float* src;
  ushort_t* dst;
  if (p < NROWS * 8) {
    const int i = p >> 3, h = p & 7;
    const int b = i & (BLAB - 1), v = i >> 10;  // i = v*B + b
    src = feat + (b * 2 + v) * 512 + h * 64;
    dst = fnb + (h * NROWS + i) * 64;
  } else {
    const int q = p - NROWS * 8;
    const int m = q >> 3, h = q & 7;
    const int b2 = m & 2047, v = m >> 11;       // m = v*B2 + b2
    src = negs + (b2 * 2 + v) * 512 + h * 64;
    dst = nnb + (h * MROWS + m) * 64;
  }
  const float4 x = *(const float4*)(src + 4 * ln);
  float ss = x.x * x.x + x.y * x.y + x.z * x.z + x.w * x.w;
#pragma unroll
  for (int d = 1; d < 16; d <<= 1) ss += __shfl_xor(ss, d, 64);
  const float inv = 1.0f / fmaxf(sqrtf(ss), 1e-12f);
  ushort4 o;
  o.x = f2bf(x.x * inv); o.y = f2bf(x.y * inv);
  o.z = f2bf(x.z * inv); o.w = f2bf(x.w * inv);
  *(ushort4*)(dst + 4 * ln) = o;
}

// lane-group reduce of (max-of-c, sum-exp-at-ref) and store reference-framed (m,S)
__device__ __forceinline__ void store_ms(float mc[4], float sa[4],
                                         float* __restrict__ gm, float* __restrict__ gs,
                                         int rowbase, int off, int lg, int ln) {
#pragma unroll
  for (int q = 0; q < 4; ++q) {
#pragma unroll
    for (int d = 1; d < 16; d <<= 1) {
      mc[q] = fmaxf(mc[q], __shfl_xor(mc[q], d, 64));
      sa[q] += __shfl_xor(sa[q], d, 64);
    }
  }
  if (ln == 0) {
#pragma unroll
    for (int q = 0; q < 4; ++q) {
      const int row = rowbase + lg * 4 + q;
      gm[row * 32 + off] = mc[q] * INVT;                      // m = max(sim)/T
      gs[row * 32 + off] = sa[q] * __expf((1.0f - mc[q]) * INVT);  // S = sum exp(x - m)
    }
  }
}

// pass A: per (head, 16 i-rows per wave), online max + sum-exp over j (self excluded
// from sum) and over m. MFMA 16x16x32 bf16, operands streamed from L2, no LDS.
// grid: 1024 = head(8) x i-tile(32) x j-split(4); 4 waves/block, wave owns 16 rows
__global__ __launch_bounds__(256) void k_passA(const ushort_t* __restrict__ fnb,
                                               const ushort_t* __restrict__ nnb,
                                               float* __restrict__ m1p, float* __restrict__ S1p,
                                               float* __restrict__ m2p, float* __restrict__ S2p) {
  const int tid  = threadIdx.x;
  const int head = blockIdx.x & 7;
  const int it   = (blockIdx.x >> 3) & 31;
  const int js   = blockIdx.x >> 8;
  const int w = tid >> 6, lane = tid & 63, lg = lane >> 4, ln = lane & 15;
  const ushort_t* fh = fnb + head * (NROWS * 64);
  const ushort_t* nh = nnb + head * (MROWS * 64);
  const int rowbase = it * 64 + w * 16;
  const int irow = rowbase + ln;

  const bf16x8 a0 = ldb(fh + irow * 64 + lg * 8);
  const bf16x8 a1 = ldb(fh + irow * 64 + 32 + lg * 8);

  float mc[4], sa[4];
#pragma unroll
  for (int q = 0; q < 4; ++q) { mc[q] = -3.0e38f; sa[q] = 0.0f; }

  const int j0 = js * 512, j1 = j0 + 512;
  const int t0 = js * 1024, t1 = t0 + 1024;

  uint4 rb0 = *(const uint4*)(fh + (j0 + ln) * 64 + lg * 8);
  uint4 rb1 = *(const uint4*)(fh + (j0 + ln) * 64 + 32 + lg * 8);
  for (int j = j0; j < j1; j += 16) {
    const int jn = j + 16;
    const ushort_t* nsrc = (jn < j1) ? (fh + (jn + ln) * 64) : (nh + (t0 + ln) * 64);
    const uint4 nb0 = *(const uint4*)(nsrc + lg * 8);
    const uint4 nb1 = *(const uint4*)(nsrc + 32 + lg * 8);
    f32x4 c = {0.0f, 0.0f, 0.0f, 0.0f};
    c = __builtin_amdgcn_mfma_f32_16x16x32_bf16(a0, __builtin_bit_cast(bf16x8, rb0), c, 0, 0, 0);
    c = __builtin_amdgcn_mfma_f32_16x16x32_bf16(a1, __builtin_bit_cast(bf16x8, rb1), c, 0, 0, 0);
    const int gj = j + ln;
#pragma unroll
    for (int q = 0; q < 4; ++q) {
      const float cv = c[q];
      mc[q] = fmaxf(mc[q], cv);
      float e = __expf(fmaf(cv, INVT, -INVT));       // exp((sim-1)/T), ref max at sim=1
      if (rowbase + lg * 4 + q == gj) e = 0.0f;      // self excluded from sum only
      sa[q] += e;
    }
    rb0 = nb0; rb1 = nb1;
  }
  store_ms(mc, sa, m1p, S1p, rowbase, head * 4 + js, lg, ln);

#pragma unroll
  for (int q = 0; q < 4; ++q) { mc[q] = -3.0e38f; sa[q] = 0.0f; }
  for (int t = t0; t < t1; t += 16) {
    const int tn = t + 16;
    const ushort_t* nsrc = nh + (((tn < t1) ? tn : t0) + ln) * 64;
    const uint4 nb0 = *(const uint4*)(nsrc + lg * 8);
    const uint4 nb1 = *(const uint4*)(nsrc + 32 + lg * 8);
    f32x4 c = {0.0f, 0.0f, 0.0f, 0.0f};
    c = __builtin_amdgcn_mfma_f32_16x16x32_bf16(a0, __builtin_bit_cast(bf16x8, rb0), c, 0, 0, 0);
    c = __builtin_amdgcn_mfma_f32_16x16x32_bf16(a1, __builtin_bit_cast(bf16x8, rb1), c, 0, 0, 0);
#pragma unroll
    for (int q = 0; q < 4; ++q) {
      const float cv = c[q];
      mc[q] = fmaxf(mc[q], cv);
      sa[q] += __expf(fmaf(cv, INVT, -INVT));
    }
    rb0 = nb0; rb1 = nb1;
  }
  store_ms(mc, sa, m2p, S2p, rowbase, head * 4 + js, lg, ln);
}

// pass B: per (i,j) max/argmax over heads via MFMA, masked log-prob accumulation
// grid: 1024 = i-tile(32) x j-tile(32); wave owns 16 i-rows x 64 j-cols
__global__ __launch_bounds__(256) void k_passB(const ushort_t* __restrict__ fnb,
                                               const float* __restrict__ m1p, const float* __restrict__ S1p,
                                               const float* __restrict__ m2p, const float* __restrict__ S2p,
                                               const u64* __restrict__ lbits,
                                               float* __restrict__ rowsum, float* __restrict__ rowcnt) {
  __shared__ float dn[64 * 9];   // stride 9: spreads the random-h reads across banks
  const int tid = threadIdx.x;
  const int it = blockIdx.x >> 5, jt = blockIdx.x & 31;
  const int ibase = it * 64, jbase = jt * 64;
  const int w = tid >> 6, lane = tid & 63, lg = lane >> 4, ln = lane & 15;

  // merge the 4 j-split partials -> dn[i_local][h] (reference's mixed-max denom)
  for (int e = tid; e < 512; e += 256) {
    const int il = e >> 3, h = e & 7;
    const float4 mq = *(const float4*)(m1p + (ibase + il) * 32 + h * 4);
    const float4 sq = *(const float4*)(S1p + (ibase + il) * 32 + h * 4);
    const float4 m2q = *(const float4*)(m2p + (ibase + il) * 32 + h * 4);
    const float4 s2q = *(const float4*)(S2p + (ibase + il) * 32 + h * 4);
    float m = fmaxf(fmaxf(mq.x, mq.y), fmaxf(mq.z, mq.w));
    float s = sq.x * __expf(mq.x - m) + sq.y * __expf(mq.y - m)
            + sq.z * __expf(mq.z - m) + sq.w * __expf(mq.w - m);
    float m2 = fmaxf(fmaxf(m2q.x, m2q.y), fmaxf(m2q.z, m2q.w));
    float s2 = s2q.x * __expf(m2q.x - m2) + s2q.y * __expf(m2q.y - m2)
             + s2q.z * __expf(m2q.z - m2) + s2q.w * __expf(m2q.w - m2);
    dn[il * 9 + h] = m + __logf(s + s2);
  }
  __syncthreads();

  const int irow = ibase + w * 16 + ln;
  float maxd[4][4];
  int besth[4][4];
#pragma unroll
  for (int sj = 0; sj < 4; ++sj)
#pragma unroll
    for (int q = 0; q < 4; ++q) { maxd[sj][q] = -3.0e38f; besth[sj][q] = 0; }

  for (int h = 0; h < 8; ++h) {
    const ushort_t* fh = fnb + h * (NROWS * 64);
    const bf16x8 a0 = ldb(fh + irow * 64 + lg * 8);
    const bf16x8 a1 = ldb(fh + irow * 64 + 32 + lg * 8);
#pragma unroll
    for (int sj = 0; sj < 4; ++sj) {
      const int jrow = jbase + sj * 16 + ln;
      const bf16x8 b0 = ldb(fh + jrow * 64 + lg * 8);
      const bf16x8 b1 = ldb(fh + jrow * 64 + 32 + lg * 8);
      f32x4 c = {0.0f, 0.0f, 0.0f, 0.0f};
      c = __builtin_amdgcn_mfma_f32_16x16x32_bf16(a0, b0, c, 0, 0, 0);
      c = __builtin_amdgcn_mfma_f32_16x16x32_bf16(a1, b1, c, 0, 0, 0);
#pragma unroll
      for (int q = 0; q < 4; ++q)
        if (c[q] > maxd[sj][q]) { maxd[sj][q] = c[q]; besth[sj][q] = h; }  // first-max tiebreak
    }
  }

  u64 lbi[4];
#pragma unroll
  for (int q = 0; q < 4; ++q) lbi[q] = lbits[(ibase + w * 16 + lg * 4 + q) & (BLAB - 1)];
  float rs[4] = {0, 0, 0, 0}, rc[4] = {0, 0, 0, 0};
#pragma unroll
  for (int sj = 0; sj < 4; ++sj) {
    const int gj = jbase + sj * 16 + ln;
    const u64 lbj = lbits[gj & (BLAB - 1)];
#pragma unroll
    for (int q = 0; q < 4; ++q) {
      const int gi = ibase + w * 16 + lg * 4 + q;
      if (gi != gj && (lbi[q] & lbj)) {
        rs[q] += maxd[sj][q] * INVT - dn[(w * 16 + lg * 4 + q) * 9 + besth[sj][q]];
        rc[q] += 1.0f;
      }
    }
  }
#pragma unroll
  for (int q = 0; q < 4; ++q) {
#pragma unroll
    for (int d = 1; d < 16; d <<= 1) {
      rs[q] += __shfl_xor(rs[q], d, 64);
      rc[q] += __shfl_xor(rc[q], d, 64);
    }
  }
  if (ln == 0) {
#pragma unroll
    for (int q = 0; q < 4; ++q) {
      const int row = ibase + w * 16 + lg * 4 + q;
      atomicAdd(&rowsum[row], rs[q]);
      atomicAdd(&rowcnt[row], rc[q]);
    }
  }
}

// final: mean over rows with cnt>0 of -(rowsum/cnt); empty -> 0
__global__ void k_final(const float* __restrict__ rowsum, const float* __restrict__ rowcnt,
                        float* __restrict__ out) {
  __shared__ float sdata[4][2];
  const int tid = threadIdx.x;
  float s = 0.0f, c = 0.0f;
  for (int i = tid; i < NROWS; i += 256) {
    const float cnt = rowcnt[i];
    if (cnt > 0.0f) { s -= rowsum[i] / cnt; c += 1.0f; }
  }
#pragma unroll
  for (int d = 32; d; d >>= 1) { s += __shfl_xor(s, d, 64); c += __shfl_xor(c, d, 64); }
  const int w = tid >> 6;
  if ((tid & 63) == 0) { sdata[w][0] = s; sdata[w][1] = c; }
  __syncthreads();
  if (tid == 0) {
    s = 0.0f; c = 0.0f;
#pragma unroll
    for (int w2 = 0; w2 < 4; ++w2) { s += sdata[w2][0]; c += sdata[w2][1]; }
    out[0] = (c > 0.0f) ? s / c : 0.0f;
  }
}

extern "C" void kernel_launch(void* const* d_in, const int* in_sizes, int n_in,
                              void* d_out, int out_size, void* d_ws, size_t ws_size,
                              hipStream_t stream) {
  const float* feat   = (const float*)d_in[0];
  const float* negs   = (const float*)d_in[1];
  const float* labels = (const float*)d_in[2];
  float* out = (float*)d_out;

  ushort_t* fnb = (ushort_t*)d_ws;             // (H,N,64) bf16 = 2 MB
  ushort_t* nnb = fnb + 8 * NROWS * 64;        // (H,M,64) bf16 = 4 MB
  float* m1p = (float*)(nnb + 8 * MROWS * 64); // (N,32) each
  float* S1p = m1p + 65536;
  float* m2p = S1p + 65536;
  float* S2p = m2p + 65536;
  float* rowsum = S2p + 65536;                 // 2048
  float* rowcnt = rowsum + 2048;               // 2048
  u64*   lbits  = (u64*)(rowcnt + 2048);       // 1024

  k_setup<<<256, 256, 0, stream>>>(labels, lbits, rowsum);
  k_norm<<<3072, 256, 0, stream>>>(feat, negs, fnb, nnb);
  k_passA<<<1024, 256, 0, stream>>>(fnb, nnb, m1p, S1p, m2p, S2p);
  k_passB<<<1024, 256, 0, stream>>>(fnb, m1p, S1p, m2p, S2p, lbits, rowsum, rowcnt);
  k_final<<<1, 256, 0, stream>>>(rowsum, rowcnt, out);
}

// Round 8
// 186.077 us; speedup vs baseline: 2.6303x; 1.2127x over previous
//
#include <hip/hip_runtime.h>

typedef unsigned long long u64;
typedef unsigned short ushort_t;
typedef __bf16 bf16x8 __attribute__((ext_vector_type(8)));
typedef float f32x4 __attribute__((ext_vector_type(4)));

#define NROWS 2048
#define MROWS 4096
#define BLAB  1024
#define INVT  (1.0f / 0.07f)
#define K2    (INVT * 1.4426950408889634f)   // (1/T) * log2(e)

__device__ __forceinline__ bf16x8 ldb(const ushort_t* p) {
  return __builtin_bit_cast(bf16x8, *(const uint4*)p);
}

__device__ __forceinline__ ushort_t f2bf(float f) {
  unsigned u = __float_as_uint(f);
  u += 0x7fff + ((u >> 16) & 1);   // RNE (inputs finite)
  return (ushort_t)(u >> 16);
}

// ---------- k_prep: L2-normalize -> bf16 (blocks < 3072) + label bitmasks/zeroing ----------
__global__ void k_prep(const float* __restrict__ feat, const float* __restrict__ negs,
                       const float* __restrict__ labels,
                       ushort_t* __restrict__ fnb, ushort_t* __restrict__ nnb,
                       u64* __restrict__ lbits, float* __restrict__ zbuf) {
  if (blockIdx.x >= 3072) {
    const int gtid = (blockIdx.x - 3072) * 256 + threadIdx.x;
    if (gtid < 4096) zbuf[gtid] = 0.0f;           // rowsum + rowcnt
    const int wid  = gtid >> 6;
    const int lane = threadIdx.x & 63;
    if (wid < BLAB) {
      float v = labels[wid * 64 + lane];
      u64 msk = __ballot(v != 0.0f);
      if (lane == 0) lbits[wid] = msk;
    }
    return;
  }
  const int wid  = blockIdx.x * 4 + ((threadIdx.x >> 6));
  const int lane = threadIdx.x & 63;
  const int g = lane >> 4, ln = lane & 15;
  const int p = wid * 4 + g;                      // (row,head) pair index
  const float* src;
  ushort_t* dst;
  if (p < NROWS * 8) {
    const int i = p >> 3, h = p & 7;
    const int b = i & (BLAB - 1), v = i >> 10;    // i = v*B + b (view-major concat)
    src = feat + (b * 2 + v) * 512 + h * 64;
    dst = fnb + (h * NROWS + i) * 64;
  } else {
    const int q = p - NROWS * 8;
    const int m = q >> 3, h = q & 7;
    const int b2 = m & 2047, v = m >> 11;         // m = v*B2 + b2
    src = negs + (b2 * 2 + v) * 512 + h * 64;
    dst = nnb + (h * MROWS + m) * 64;
  }
  const float4 x = *(const float4*)(src + 4 * ln);
  float ss = x.x * x.x + x.y * x.y + x.z * x.z + x.w * x.w;
#pragma unroll
  for (int d = 1; d < 16; d <<= 1) ss += __shfl_xor(ss, d, 64);
  const float inv = 1.0f / fmaxf(sqrtf(ss), 1e-12f);
  ushort4 o;
  o.x = f2bf(x.x * inv); o.y = f2bf(x.y * inv);
  o.z = f2bf(x.z * inv); o.w = f2bf(x.w * inv);
  *(ushort4*)(dst + 4 * ln) = o;
}

// reduce (max, sum) over the ln dimension; store reference-framed (m, S); reset accums
__device__ __forceinline__ void store_ms4(float mc[4][4], float sa[4][4],
                                          float* __restrict__ gm, float* __restrict__ gs,
                                          int base, int off, int lg, int ln) {
#pragma unroll
  for (int rs = 0; rs < 4; ++rs) {
#pragma unroll
    for (int q = 0; q < 4; ++q) {
      float m = mc[rs][q], s = sa[rs][q];
#pragma unroll
      for (int d = 1; d < 16; d <<= 1) {
        m = fmaxf(m, __shfl_xor(m, d, 64));
        s += __shfl_xor(s, d, 64);
      }
      if (ln == 0) {
        const int row = base + rs * 16 + lg * 4 + q;
        gm[row * 128 + off] = m * INVT;                 // m = max(sim)/T
        gs[row * 128 + off] = s * exp2f((1.0f - m) * K2); // S = sum exp(x - m)
      }
      mc[rs][q] = -3.0e38f; sa[rs][q] = 0.0f;
    }
  }
}

// pass A: online max + sum-exp over j (self excluded from sum only) and over m.
// Wave owns 64 i-rows (4 A-frag pairs in regs); block = 4 waves x 64 rows sharing
// the same B column stream (L1 reuse). grid 1024 = head(8) x rowblk(8) x js(16).
__global__ __launch_bounds__(256, 4) void k_passA(const ushort_t* __restrict__ fnb,
                                                  const ushort_t* __restrict__ nnb,
                                                  float* __restrict__ m1p, float* __restrict__ S1p,
                                                  float* __restrict__ m2p, float* __restrict__ S2p) {
  const int tid  = threadIdx.x;
  const int head = blockIdx.x & 7;
  const int rbk  = (blockIdx.x >> 3) & 7;
  const int js   = blockIdx.x >> 6;
  const int w = tid >> 6, lane = tid & 63, lg = lane >> 4, ln = lane & 15;
  const ushort_t* fh = fnb + head * (NROWS * 64);
  const ushort_t* nh = nnb + head * (MROWS * 64);
  const int base = rbk * 256 + w * 64;
  const int off  = head * 16 + js;

  bf16x8 a0[4], a1[4];
#pragma unroll
  for (int rs = 0; rs < 4; ++rs) {
    const ushort_t* ap = fh + (base + rs * 16 + ln) * 64 + lg * 8;
    a0[rs] = ldb(ap); a1[rs] = ldb(ap + 32);
  }
  float mc[4][4], sa[4][4];
#pragma unroll
  for (int rs = 0; rs < 4; ++rs)
#pragma unroll
    for (int q = 0; q < 4; ++q) { mc[rs][q] = -3.0e38f; sa[rs][q] = 0.0f; }

  const int j0 = js * 128;    // 8 j-tiles of 16
  const int t0 = js * 256;    // 16 t-tiles of 16

  uint4 rb0 = *(const uint4*)(fh + (j0 + ln) * 64 + lg * 8);
  uint4 rb1 = *(const uint4*)(fh + (j0 + ln) * 64 + 32 + lg * 8);
  for (int ji = 0; ji < 8; ++ji) {
    const int j = j0 + ji * 16;
    const ushort_t* nsrc = (ji < 7) ? (fh + (j + 16 + ln) * 64) : (nh + (t0 + ln) * 64);
    const uint4 nb0 = *(const uint4*)(nsrc + lg * 8);
    const uint4 nb1 = *(const uint4*)(nsrc + 32 + lg * 8);
    const int gj = j + ln;
#pragma unroll
    for (int rs = 0; rs < 4; ++rs) {
      f32x4 c = {0.0f, 0.0f, 0.0f, 0.0f};
      c = __builtin_amdgcn_mfma_f32_16x16x32_bf16(a0[rs], __builtin_bit_cast(bf16x8, rb0), c, 0, 0, 0);
      c = __builtin_amdgcn_mfma_f32_16x16x32_bf16(a1[rs], __builtin_bit_cast(bf16x8, rb1), c, 0, 0, 0);
#pragma unroll
      for (int q = 0; q < 4; ++q) {
        const float cv = c[q];
        mc[rs][q] = fmaxf(mc[rs][q], cv);                 // self included in max
        float e = exp2f(fmaf(cv, K2, -K2));               // exp((sim-1)/T)
        if (base + rs * 16 + lg * 4 + q == gj) e = 0.0f;  // self excluded from sum
        sa[rs][q] += e;
      }
    }
    rb0 = nb0; rb1 = nb1;
  }
  store_ms4(mc, sa, m1p, S1p, base, off, lg, ln);

  for (int ti = 0; ti < 16; ++ti) {
    const int t = t0 + ti * 16;
    const ushort_t* nsrc = nh + (((ti < 15) ? (t + 16) : t0) + ln) * 64;
    const uint4 nb0 = *(const uint4*)(nsrc + lg * 8);
    const uint4 nb1 = *(const uint4*)(nsrc + 32 + lg * 8);
#pragma unroll
    for (int rs = 0; rs < 4; ++rs) {
      f32x4 c = {0.0f, 0.0f, 0.0f, 0.0f};
      c = __builtin_amdgcn_mfma_f32_16x16x32_bf16(a0[rs], __builtin_bit_cast(bf16x8, rb0), c, 0, 0, 0);
      c = __builtin_amdgcn_mfma_f32_16x16x32_bf16(a1[rs], __builtin_bit_cast(bf16x8, rb1), c, 0, 0, 0);
#pragma unroll
      for (int q = 0; q < 4; ++q) {
        const float cv = c[q];
        mc[rs][q] = fmaxf(mc[rs][q], cv);
        sa[rs][q] += exp2f(fmaf(cv, K2, -K2));
      }
    }
    rb0 = nb0; rb1 = nb1;
  }
  store_ms4(mc, sa, m2p, S2p, base, off, lg, ln);
}

// pass B: per (i,j) max-over-heads with bestdn tracked in regs; masked accumulation.
// grid: 1024 = i-tile(32) x j-tile(32); wave owns 16 i-rows x 64 j-cols.
__global__ __launch_bounds__(256, 3) void k_passB(const ushort_t* __restrict__ fnb,
                                                  const float* __restrict__ m1p, const float* __restrict__ S1p,
                                                  const float* __restrict__ m2p, const float* __restrict__ S2p,
                                                  const u64* __restrict__ lbits,
                                                  float* __restrict__ rowsum, float* __restrict__ rowcnt) {
  __shared__ float dn[64 * 9];
  const int tid = threadIdx.x;
  const int it = blockIdx.x >> 5, jt = blockIdx.x & 31;
  const int ibase = it * 64, jbase = jt * 64;
  const int w = tid >> 6, lane = tid & 63, lg = lane >> 4, ln = lane & 15;

  // merge the 16 j-split partials -> dn[i_local][h] (reference's mixed-max denom)
  for (int e = tid; e < 512; e += 256) {
    const int il = e >> 3, h = e & 7;
    const int bidx = (ibase + il) * 128 + h * 16;
    float4 mq[4], sq[4], m2q[4], s2q[4];
#pragma unroll
    for (int k = 0; k < 4; ++k) {
      mq[k]  = *(const float4*)(m1p + bidx + 4 * k);
      sq[k]  = *(const float4*)(S1p + bidx + 4 * k);
      m2q[k] = *(const float4*)(m2p + bidx + 4 * k);
      s2q[k] = *(const float4*)(S2p + bidx + 4 * k);
    }
    float m = -3.0e38f, m2 = -3.0e38f;
#pragma unroll
    for (int k = 0; k < 4; ++k) {
      m  = fmaxf(m,  fmaxf(fmaxf(mq[k].x,  mq[k].y),  fmaxf(mq[k].z,  mq[k].w)));
      m2 = fmaxf(m2, fmaxf(fmaxf(m2q[k].x, m2q[k].y), fmaxf(m2q[k].z, m2q[k].w)));
    }
    float s = 0.0f, s2 = 0.0f;
#pragma unroll
    for (int k = 0; k < 4; ++k) {
      s  += sq[k].x  * __expf(mq[k].x  - m)  + sq[k].y  * __expf(mq[k].y  - m)
          + sq[k].z  * __expf(mq[k].z  - m)  + sq[k].w  * __expf(mq[k].w  - m);
      s2 += s2q[k].x * __expf(m2q[k].x - m2) + s2q[k].y * __expf(m2q[k].y - m2)
          + s2q[k].z * __expf(m2q[k].z - m2) + s2q[k].w * __expf(m2q[k].w - m2);
    }
    dn[il * 9 + h] = m + __logf(s + s2);
  }
  __syncthreads();

  // per-lane copy of denom for its 4 i-rows (statically indexed in the h-unroll)
  float dnr[4][8];
#pragma unroll
  for (int q = 0; q < 4; ++q) {
    const int il = w * 16 + lg * 4 + q;
#pragma unroll
    for (int h = 0; h < 8; ++h) dnr[q][h] = dn[il * 9 + h];
  }

  const int irow = ibase + w * 16 + ln;
  float maxd[4][4], bestdn[4][4];
#pragma unroll
  for (int sj = 0; sj < 4; ++sj)
#pragma unroll
    for (int q = 0; q < 4; ++q) { maxd[sj][q] = -3.0e38f; bestdn[sj][q] = 0.0f; }

#pragma unroll
  for (int h = 0; h < 8; ++h) {
    const ushort_t* fh = fnb + h * (NROWS * 64);
    const bf16x8 a0 = ldb(fh + irow * 64 + lg * 8);
    const bf16x8 a1 = ldb(fh + irow * 64 + 32 + lg * 8);
#pragma unroll
    for (int sj = 0; sj < 4; ++sj) {
      const int jrow = jbase + sj * 16 + ln;
      const bf16x8 b0 = ldb(fh + jrow * 64 + lg * 8);
      const bf16x8 b1 = ldb(fh + jrow * 64 + 32 + lg * 8);
      f32x4 c = {0.0f, 0.0f, 0.0f, 0.0f};
      c = __builtin_amdgcn_mfma_f32_16x16x32_bf16(a0, b0, c, 0, 0, 0);
      c = __builtin_amdgcn_mfma_f32_16x16x32_bf16(a1, b1, c, 0, 0, 0);
#pragma unroll
      for (int q = 0; q < 4; ++q)
        if (c[q] > maxd[sj][q]) { maxd[sj][q] = c[q]; bestdn[sj][q] = dnr[q][h]; }  // first-max tiebreak
    }
  }

  u64 lbi[4];
#pragma unroll
  for (int q = 0; q < 4; ++q) lbi[q] = lbits[(ibase + w * 16 + lg * 4 + q) & (BLAB - 1)];
  float rs[4] = {0, 0, 0, 0}, rc[4] = {0, 0, 0, 0};
#pragma unroll
  for (int sj = 0; sj < 4; ++sj) {
    const int gj = jbase + sj * 16 + ln;
    const u64 lbj = lbits[gj & (BLAB - 1)];
#pragma unroll
    for (int q = 0; q < 4; ++q) {
      const int gi = ibase + w * 16 + lg * 4 + q;
      if (gi != gj && (lbi[q] & lbj)) {
        rs[q] += maxd[sj][q] * INVT - bestdn[sj][q];
        rc[q] += 1.0f;
      }
    }
  }
#pragma unroll
  for (int q = 0; q < 4; ++q) {
#pragma unroll
    for (int d = 1; d < 16; d <<= 1) {
      rs[q] += __shfl_xor(rs[q], d, 64);
      rc[q] += __shfl_xor(rc[q], d, 64);
    }
  }
  if (ln == 0) {
#pragma unroll
    for (int q = 0; q < 4; ++q) {
      const int row = ibase + w * 16 + lg * 4 + q;
      atomicAdd(&rowsum[row], rs[q]);
      atomicAdd(&rowcnt[row], rc[q]);
    }
  }
}

// final: mean over rows with cnt>0 of -(rowsum/cnt); empty -> 0
__global__ void k_final(const float* __restrict__ rowsum, const float* __restrict__ rowcnt,
                        float* __restrict__ out) {
  __shared__ float sdata[4][2];
  const int tid = threadIdx.x;
  float s = 0.0f, c = 0.0f;
  for (int i = tid; i < NROWS; i += 256) {
    const float cnt = rowcnt[i];
    if (cnt > 0.0f) { s -= rowsum[i] / cnt; c += 1.0f; }
  }
#pragma unroll
  for (int d = 32; d; d >>= 1) { s += __shfl_xor(s, d, 64); c += __shfl_xor(c, d, 64); }
  const int w = tid >> 6;
  if ((tid & 63) == 0) { sdata[w][0] = s; sdata[w][1] = c; }
  __syncthreads();
  if (tid == 0) {
    s = 0.0f; c = 0.0f;
#pragma unroll
    for (int w2 = 0; w2 < 4; ++w2) { s += sdata[w2][0]; c += sdata[w2][1]; }
    out[0] = (c > 0.0f) ? s / c : 0.0f;
  }
}

extern "C" void kernel_launch(void* const* d_in, const int* in_sizes, int n_in,
                              void* d_out, int out_size, void* d_ws, size_t ws_size,
                              hipStream_t stream) {
  const float* feat   = (const float*)d_in[0];
  const float* negs   = (const float*)d_in[1];
  const float* labels = (const float*)d_in[2];
  float* out = (float*)d_out;

  ushort_t* fnb = (ushort_t*)d_ws;              // (H,N,64) bf16 = 2 MB
  ushort_t* nnb = fnb + 8 * NROWS * 64;         // (H,M,64) bf16 = 4 MB
  float* m1p = (float*)(nnb + 8 * MROWS * 64);  // (N,128) each = 1 MB x 4
  float* S1p = m1p + NROWS * 128;
  float* m2p = S1p + NROWS * 128;
  float* S2p = m2p + NROWS * 128;
  float* rowsum = S2p + NROWS * 128;            // 2048
  float* rowcnt = rowsum + 2048;                // 2048
  u64*   lbits  = (u64*)(rowcnt + 2048);        // 1024

  k_prep<<<3328, 256, 0, stream>>>(feat, negs, labels, fnb, nnb, lbits, rowsum);
  k_passA<<<1024, 256, 0, stream>>>(fnb, nnb, m1p, S1p, m2p, S2p);
  k_passB<<<1024, 256, 0, stream>>>(fnb, m1p, S1p, m2p, S2p, lbits, rowsum, rowcnt);
  k_final<<<1, 256, 0, stream>>>(rowsum, rowcnt, out);
}

// Round 10
// 173.642 us; speedup vs baseline: 2.8187x; 1.0716x over previous
//
#include <hip/hip_runtime.h>

typedef unsigned long long u64;
typedef unsigned short ushort_t;
typedef __bf16 bf16x8 __attribute__((ext_vector_type(8)));
typedef float f32x4 __attribute__((ext_vector_type(4)));

#define NROWS 2048
#define MROWS 4096
#define BLAB  1024
#define INVT  (1.0f / 0.07f)
#define K2    (INVT * 1.4426950408889634f)   // (1/T) * log2(e)

__device__ __forceinline__ bf16x8 ldb(const ushort_t* p) {
  return __builtin_bit_cast(bf16x8, *(const uint4*)p);
}

__device__ __forceinline__ ushort_t f2bf(float f) {
  unsigned u = __float_as_uint(f);
  u += 0x7fff + ((u >> 16) & 1);   // RNE (inputs finite)
  return (ushort_t)(u >> 16);
}

// ---------- k_prep: L2-normalize -> bf16 (blocks < 3072) + label bitmasks/zeroing ----------
__global__ void k_prep(const float* __restrict__ feat, const float* __restrict__ negs,
                       const float* __restrict__ labels,
                       ushort_t* __restrict__ fnb, ushort_t* __restrict__ nnb,
                       u64* __restrict__ lbits, float* __restrict__ zbuf) {
  if (blockIdx.x >= 3072) {
    const int gtid = (blockIdx.x - 3072) * 256 + threadIdx.x;
    if (gtid < 4096) zbuf[gtid] = 0.0f;           // rowsum + rowcnt
    const int wid  = gtid >> 6;
    const int lane = threadIdx.x & 63;
    if (wid < BLAB) {
      float v = labels[wid * 64 + lane];
      u64 msk = __ballot(v != 0.0f);
      if (lane == 0) lbits[wid] = msk;
    }
    return;
  }
  const int wid  = blockIdx.x * 4 + ((threadIdx.x >> 6));
  const int lane = threadIdx.x & 63;
  const int g = lane >> 4, ln = lane & 15;
  const int p = wid * 4 + g;                      // (row,head) pair index
  const float* src;
  ushort_t* dst;
  if (p < NROWS * 8) {
    const int i = p >> 3, h = p & 7;
    const int b = i & (BLAB - 1), v = i >> 10;    // i = v*B + b (view-major concat)
    src = feat + (b * 2 + v) * 512 + h * 64;
    dst = fnb + (h * NROWS + i) * 64;
  } else {
    const int q = p - NROWS * 8;
    const int m = q >> 3, h = q & 7;
    const int b2 = m & 2047, v = m >> 11;         // m = v*B2 + b2
    src = negs + (b2 * 2 + v) * 512 + h * 64;
    dst = nnb + (h * MROWS + m) * 64;
  }
  const float4 x = *(const float4*)(src + 4 * ln);
  float ss = x.x * x.x + x.y * x.y + x.z * x.z + x.w * x.w;
#pragma unroll
  for (int d = 1; d < 16; d <<= 1) ss += __shfl_xor(ss, d, 64);
  const float inv = 1.0f / fmaxf(sqrtf(ss), 1e-12f);
  ushort4 o;
  o.x = f2bf(x.x * inv); o.y = f2bf(x.y * inv);
  o.z = f2bf(x.z * inv); o.w = f2bf(x.w * inv);
  *(ushort4*)(dst + 4 * ln) = o;
}

// reduce (max, sum) over the ln dimension; store reference-framed (m, S); reset accums
__device__ __forceinline__ void store_ms4(float mc[4][4], float sa[4][4],
                                          float* __restrict__ gm, float* __restrict__ gs,
                                          int base, int off, int lg, int ln) {
#pragma unroll
  for (int rs = 0; rs < 4; ++rs) {
#pragma unroll
    for (int q = 0; q < 4; ++q) {
      float m = mc[rs][q], s = sa[rs][q];
#pragma unroll
      for (int d = 1; d < 16; d <<= 1) {
        m = fmaxf(m, __shfl_xor(m, d, 64));
        s += __shfl_xor(s, d, 64);
      }
      if (ln == 0) {
        const int row = base + rs * 16 + lg * 4 + q;
        gm[row * 128 + off] = m * INVT;                 // m = max(sim)/T
        gs[row * 128 + off] = s * exp2f((1.0f - m) * K2); // S = sum exp(x - m)
      }
      mc[rs][q] = -3.0e38f; sa[rs][q] = 0.0f;
    }
  }
}

// pass A: online max + sum-exp over j (self excluded from sum only) and over m.
// Wave owns 64 i-rows (4 A-frag pairs in regs); block = 4 waves x 64 rows sharing
// the same B column stream (L1 reuse). grid 1024 = head(8) x rowblk(8) x js(16).
// launch_bounds min-waves=2: VGPR cap 256. (256,4) capped at 64 VGPR and spilled
// ~96 MB/dispatch to scratch -> passA was pure spill-BW-bound (r8 counters).
__global__ __launch_bounds__(256, 2) void k_passA(const ushort_t* __restrict__ fnb,
                                                  const ushort_t* __restrict__ nnb,
                                                  float* __restrict__ m1p, float* __restrict__ S1p,
                                                  float* __restrict__ m2p, float* __restrict__ S2p) {
  const int tid  = threadIdx.x;
  const int head = blockIdx.x & 7;
  const int rbk  = (blockIdx.x >> 3) & 7;
  const int js   = blockIdx.x >> 6;
  const int w = tid >> 6, lane = tid & 63, lg = lane >> 4, ln = lane & 15;
  const ushort_t* fh = fnb + head * (NROWS * 64);
  const ushort_t* nh = nnb + head * (MROWS * 64);
  const int base = rbk * 256 + w * 64;
  const int off  = head * 16 + js;

  bf16x8 a0[4], a1[4];
#pragma unroll
  for (int rs = 0; rs < 4; ++rs) {
    const ushort_t* ap = fh + (base + rs * 16 + ln) * 64 + lg * 8;
    a0[rs] = ldb(ap); a1[rs] = ldb(ap + 32);
  }
  float mc[4][4], sa[4][4];
#pragma unroll
  for (int rs = 0; rs < 4; ++rs)
#pragma unroll
    for (int q = 0; q < 4; ++q) { mc[rs][q] = -3.0e38f; sa[rs][q] = 0.0f; }

  const int j0 = js * 128;    // 8 j-tiles of 16
  const int t0 = js * 256;    // 16 t-tiles of 16

  uint4 rb0 = *(const uint4*)(fh + (j0 + ln) * 64 + lg * 8);
  uint4 rb1 = *(const uint4*)(fh + (j0 + ln) * 64 + 32 + lg * 8);
  for (int ji = 0; ji < 8; ++ji) {
    const int j = j0 + ji * 16;
    const ushort_t* nsrc = (ji < 7) ? (fh + (j + 16 + ln) * 64) : (nh + (t0 + ln) * 64);
    const uint4 nb0 = *(const uint4*)(nsrc + lg * 8);
    const uint4 nb1 = *(const uint4*)(nsrc + 32 + lg * 8);
    const int gj = j + ln;
#pragma unroll
    for (int rs = 0; rs < 4; ++rs) {
      f32x4 c = {0.0f, 0.0f, 0.0f, 0.0f};
      c = __builtin_amdgcn_mfma_f32_16x16x32_bf16(a0[rs], __builtin_bit_cast(bf16x8, rb0), c, 0, 0, 0);
      c = __builtin_amdgcn_mfma_f32_16x16x32_bf16(a1[rs], __builtin_bit_cast(bf16x8, rb1), c, 0, 0, 0);
#pragma unroll
      for (int q = 0; q < 4; ++q) {
        const float cv = c[q];
        mc[rs][q] = fmaxf(mc[rs][q], cv);                 // self included in max
        float e = exp2f(fmaf(cv, K2, -K2));               // exp((sim-1)/T)
        if (base + rs * 16 + lg * 4 + q == gj) e = 0.0f;  // self excluded from sum
        sa[rs][q] += e;
      }
    }
    rb0 = nb0; rb1 = nb1;
  }
  store_ms4(mc, sa, m1p, S1p, base, off, lg, ln);

  for (int ti = 0; ti < 16; ++ti) {
    const int t = t0 + ti * 16;
    const ushort_t* nsrc = nh + (((ti < 15) ? (t + 16) : t0) + ln) * 64;
    const uint4 nb0 = *(const uint4*)(nsrc + lg * 8);
    const uint4 nb1 = *(const uint4*)(nsrc + 32 + lg * 8);
#pragma unroll
    for (int rs = 0; rs < 4; ++rs) {
      f32x4 c = {0.0f, 0.0f, 0.0f, 0.0f};
      c = __builtin_amdgcn_mfma_f32_16x16x32_bf16(a0[rs], __builtin_bit_cast(bf16x8, rb0), c, 0, 0, 0);
      c = __builtin_amdgcn_mfma_f32_16x16x32_bf16(a1[rs], __builtin_bit_cast(bf16x8, rb1), c, 0, 0, 0);
#pragma unroll
      for (int q = 0; q < 4; ++q) {
        const float cv = c[q];
        mc[rs][q] = fmaxf(mc[rs][q], cv);
        sa[rs][q] += exp2f(fmaf(cv, K2, -K2));
      }
    }
    rb0 = nb0; rb1 = nb1;
  }
  store_ms4(mc, sa, m2p, S2p, base, off, lg, ln);
}

// pass B: per (i,j) max-over-heads with bestdn tracked in regs; masked accumulation.
// grid: 1024 = i-tile(32) x j-tile(32); wave owns 16 i-rows x 64 j-cols.
// launch_bounds min-waves=2 (VGPR cap 256) for the same spill reason as passA.
__global__ __launch_bounds__(256, 2) void k_passB(const ushort_t* __restrict__ fnb,
                                                  const float* __restrict__ m1p, const float* __restrict__ S1p,
                                                  const float* __restrict__ m2p, const float* __restrict__ S2p,
                                                  const u64* __restrict__ lbits,
                                                  float* __restrict__ rowsum, float* __restrict__ rowcnt) {
  __shared__ float dn[64 * 9];
  const int tid = threadIdx.x;
  const int it = blockIdx.x >> 5, jt = blockIdx.x & 31;
  const int ibase = it * 64, jbase = jt * 64;
  const int w = tid >> 6, lane = tid & 63, lg = lane >> 4, ln = lane & 15;

  // merge the 16 j-split partials -> dn[i_local][h] (reference's mixed-max denom)
  for (int e = tid; e < 512; e += 256) {
    const int il = e >> 3, h = e & 7;
    const int bidx = (ibase + il) * 128 + h * 16;
    float4 mq[4], sq[4], m2q[4], s2q[4];
#pragma unroll
    for (int k = 0; k < 4; ++k) {
      mq[k]  = *(const float4*)(m1p + bidx + 4 * k);
      sq[k]  = *(const float4*)(S1p + bidx + 4 * k);
      m2q[k] = *(const float4*)(m2p + bidx + 4 * k);
      s2q[k] = *(const float4*)(S2p + bidx + 4 * k);
    }
    float m = -3.0e38f, m2 = -3.0e38f;
#pragma unroll
    for (int k = 0; k < 4; ++k) {
      m  = fmaxf(m,  fmaxf(fmaxf(mq[k].x,  mq[k].y),  fmaxf(mq[k].z,  mq[k].w)));
      m2 = fmaxf(m2, fmaxf(fmaxf(m2q[k].x, m2q[k].y), fmaxf(m2q[k].z, m2q[k].w)));
    }
    float s = 0.0f, s2 = 0.0f;
#pragma unroll
    for (int k = 0; k < 4; ++k) {
      s  += sq[k].x  * __expf(mq[k].x  - m)  + sq[k].y  * __expf(mq[k].y  - m)
          + sq[k].z  * __expf(mq[k].z  - m)  + sq[k].w  * __expf(mq[k].w  - m);
      s2 += s2q[k].x * __expf(m2q[k].x - m2) + s2q[k].y * __expf(m2q[k].y - m2)
          + s2q[k].z * __expf(m2q[k].z - m2) + s2q[k].w * __expf(m2q[k].w - m2);
    }
    dn[il * 9 + h] = m + __logf(s + s2);
  }
  __syncthreads();

  // per-lane copy of denom for its 4 i-rows (statically indexed in the h-unroll)
  float dnr[4][8];
#pragma unroll
  for (int q = 0; q < 4; ++q) {
    const int il = w * 16 + lg * 4 + q;
#pragma unroll
    for (int h = 0; h < 8; ++h) dnr[q][h] = dn[il * 9 + h];
  }

  const int irow = ibase + w * 16 + ln;
  float maxd[4][4], bestdn[4][4];
#pragma unroll
  for (int sj = 0; sj < 4; ++sj)
#pragma unroll
    for (int q = 0; q < 4; ++q) { maxd[sj][q] = -3.0e38f; bestdn[sj][q] = 0.0f; }

#pragma unroll
  for (int h = 0; h < 8; ++h) {
    const ushort_t* fh = fnb + h * (NROWS * 64);
    const bf16x8 a0 = ldb(fh + irow * 64 + lg * 8);
    const bf16x8 a1 = ldb(fh + irow * 64 + 32 + lg * 8);
#pragma unroll
    for (int sj = 0; sj < 4; ++sj) {
      const int jrow = jbase + sj * 16 + ln;
      const bf16x8 b0 = ldb(fh + jrow * 64 + lg * 8);
      const bf16x8 b1 = ldb(fh + jrow * 64 + 32 + lg * 8);
      f32x4 c = {0.0f, 0.0f, 0.0f, 0.0f};
      c = __builtin_amdgcn_mfma_f32_16x16x32_bf16(a0, b0, c, 0, 0, 0);
      c = __builtin_amdgcn_mfma_f32_16x16x32_bf16(a1, b1, c, 0, 0, 0);
#pragma unroll
      for (int q = 0; q < 4; ++q)
        if (c[q] > maxd[sj][q]) { maxd[sj][q] = c[q]; bestdn[sj][q] = dnr[q][h]; }  // first-max tiebreak
    }
  }

  u64 lbi[4];
#pragma unroll
  for (int q = 0; q < 4; ++q) lbi[q] = lbits[(ibase + w * 16 + lg * 4 + q) & (BLAB - 1)];
  float rs[4] = {0, 0, 0, 0}, rc[4] = {0, 0, 0, 0};
#pragma unroll
  for (int sj = 0; sj < 4; ++sj) {
    const int gj = jbase + sj * 16 + ln;
    const u64 lbj = lbits[gj & (BLAB - 1)];
#pragma unroll
    for (int q = 0; q < 4; ++q) {
      const int gi = ibase + w * 16 + lg * 4 + q;
      if (gi != gj && (lbi[q] & lbj)) {
        rs[q] += maxd[sj][q] * INVT - bestdn[sj][q];
        rc[q] += 1.0f;
      }
    }
  }
#pragma unroll
  for (int q = 0; q < 4; ++q) {
#pragma unroll
    for (int d = 1; d < 16; d <<= 1) {
      rs[q] += __shfl_xor(rs[q], d, 64);
      rc[q] += __shfl_xor(rc[q], d, 64);
    }
  }
  if (ln == 0) {
#pragma unroll
    for (int q = 0; q < 4; ++q) {
      const int row = ibase + w * 16 + lg * 4 + q;
      atomicAdd(&rowsum[row], rs[q]);
      atomicAdd(&rowcnt[row], rc[q]);
    }
  }
}

// final: mean over rows with cnt>0 of -(rowsum/cnt); empty -> 0
__global__ void k_final(const float* __restrict__ rowsum, const float* __restrict__ rowcnt,
                        float* __restrict__ out) {
  __shared__ float sdata[4][2];
  const int tid = threadIdx.x;
  float s = 0.0f, c = 0.0f;
  for (int i = tid; i < NROWS; i += 256) {
    const float cnt = rowcnt[i];
    if (cnt > 0.0f) { s -= rowsum[i] / cnt; c += 1.0f; }
  }
#pragma unroll
  for (int d = 32; d; d >>= 1) { s += __shfl_xor(s, d, 64); c += __shfl_xor(c, d, 64); }
  const int w = tid >> 6;
  if ((tid & 63) == 0) { sdata[w][0] = s; sdata[w][1] = c; }
  __syncthreads();
  if (tid == 0) {
    s = 0.0f; c = 0.0f;
#pragma unroll
    for (int w2 = 0; w2 < 4; ++w2) { s += sdata[w2][0]; c += sdata[w2][1]; }
    out[0] = (c > 0.0f) ? s / c : 0.0f;
  }
}

extern "C" void kernel_launch(void* const* d_in, const int* in_sizes, int n_in,
                              void* d_out, int out_size, void* d_ws, size_t ws_size,
                              hipStream_t stream) {
  const float* feat   = (const float*)d_in[0];
  const float* negs   = (const float*)d_in[1];
  const float* labels = (const float*)d_in[2];
  float* out = (float*)d_out;

  ushort_t* fnb = (ushort_t*)d_ws;              // (H,N,64) bf16 = 2 MB
  ushort_t* nnb = fnb + 8 * NROWS * 64;         // (H,M,64) bf16 = 4 MB
  float* m1p = (float*)(nnb + 8 * MROWS * 64);  // (N,128) each = 1 MB x 4
  float* S1p = m1p + NROWS * 128;
  float* m2p = S1p + NROWS * 128;
  float* S2p = m2p + NROWS * 128;
  float* rowsum = S2p + NROWS * 128;            // 2048
  float* rowcnt = rowsum + 2048;                // 2048
  u64*   lbits  = (u64*)(rowcnt + 2048);        // 1024

  k_prep<<<3328, 256, 0, stream>>>(feat, negs, labels, fnb, nnb, lbits, rowsum);
  k_passA<<<1024, 256, 0, stream>>>(fnb, nnb, m1p, S1p, m2p, S2p);
  k_passB<<<1024, 256, 0, stream>>>(fnb, m1p, S1p, m2p, S2p, lbits, rowsum, rowcnt);
  k_final<<<1, 256, 0, stream>>>(rowsum, rowcnt, out);
}

// Round 13
// 163.645 us; speedup vs baseline: 2.9909x; 1.0611x over previous
//
#include <hip/hip_runtime.h>

typedef unsigned long long u64;
typedef unsigned short ushort_t;
typedef __bf16 bf16x8 __attribute__((ext_vector_type(8)));
typedef float f32x4 __attribute__((ext_vector_type(4)));

#define NROWS 2048
#define MROWS 4096
#define BLAB  1024
#define INVT  (1.0f / 0.07f)
#define K2    (INVT * 1.4426950408889634f)   // (1/T) * log2(e)

__device__ __forceinline__ bf16x8 ldb(const ushort_t* p) {
  return __builtin_bit_cast(bf16x8, *(const uint4*)p);
}

__device__ __forceinline__ ushort_t f2bf(float f) {
  unsigned u = __float_as_uint(f);
  u += 0x7fff + ((u >> 16) & 1);   // RNE (inputs finite)
  return (ushort_t)(u >> 16);
}

// ---------- k_prep: L2-normalize -> bf16 (blocks < 3072) + label bitmasks/zeroing ----------
__global__ void k_prep(const float* __restrict__ feat, const float* __restrict__ negs,
                       const float* __restrict__ labels,
                       ushort_t* __restrict__ fnb, ushort_t* __restrict__ nnb,
                       u64* __restrict__ lbits, float* __restrict__ zbuf) {
  if (blockIdx.x >= 3072) {
    const int gtid = (blockIdx.x - 3072) * 256 + threadIdx.x;
    if (gtid < 4096) zbuf[gtid] = 0.0f;           // rowsum + rowcnt
    const int wid  = gtid >> 6;
    const int lane = threadIdx.x & 63;
    if (wid < BLAB) {
      float v = labels[wid * 64 + lane];
      u64 msk = __ballot(v != 0.0f);
      if (lane == 0) lbits[wid] = msk;
    }
    return;
  }
  const int wid  = blockIdx.x * 4 + ((threadIdx.x >> 6));
  const int lane = threadIdx.x & 63;
  const int g = lane >> 4, ln = lane & 15;
  const int p = wid * 4 + g;                      // (row,head) pair index
  const float* src;
  ushort_t* dst;
  if (p < NROWS * 8) {
    const int i = p >> 3, h = p & 7;
    const int b = i & (BLAB - 1), v = i >> 10;    // i = v*B + b (view-major concat)
    src = feat + (b * 2 + v) * 512 + h * 64;
    dst = fnb + (h * NROWS + i) * 64;
  } else {
    const int q = p - NROWS * 8;
    const int m = q >> 3, h = q & 7;
    const int b2 = m & 2047, v = m >> 11;         // m = v*B2 + b2
    src = negs + (b2 * 2 + v) * 512 + h * 64;
    dst = nnb + (h * MROWS + m) * 64;
  }
  const float4 x = *(const float4*)(src + 4 * ln);
  float ss = x.x * x.x + x.y * x.y + x.z * x.z + x.w * x.w;
#pragma unroll
  for (int d = 1; d < 16; d <<= 1) ss += __shfl_xor(ss, d, 64);
  const float inv = 1.0f / fmaxf(sqrtf(ss), 1e-12f);
  ushort4 o;
  o.x = f2bf(x.x * inv); o.y = f2bf(x.y * inv);
  o.z = f2bf(x.z * inv); o.w = f2bf(x.w * inv);
  *(ushort4*)(dst + 4 * ln) = o;
}

// reduce (max, sum) over the ln dimension; store reference-framed (m, S); reset accums
__device__ __forceinline__ void store_ms4(float mc[4][4], float sa[4][4],
                                          float* __restrict__ gm, float* __restrict__ gs,
                                          int base, int off, int lg, int ln) {
#pragma unroll
  for (int rs = 0; rs < 4; ++rs) {
#pragma unroll
    for (int q = 0; q < 4; ++q) {
      float m = mc[rs][q], s = sa[rs][q];
#pragma unroll
      for (int d = 1; d < 16; d <<= 1) {
        m = fmaxf(m, __shfl_xor(m, d, 64));
        s += __shfl_xor(s, d, 64);
      }
      if (ln == 0) {
        const int row = base + rs * 16 + lg * 4 + q;
        gm[row * 128 + off] = m * INVT;                 // m = max(sim)/T
        gs[row * 128 + off] = s * exp2f((1.0f - m) * K2); // S = sum exp(x - m)
      }
      mc[rs][q] = -3.0e38f; sa[rs][q] = 0.0f;
    }
  }
}

// pass A: online max + sum-exp over j (self excluded from sum only) and over m.
// Wave owns 64 i-rows (4 A-frag pairs in regs). Flat stream of 24 B-tiles
// (8 f-tiles then 16 n-tiles) consumed through a DEPTH-2 prefetch pipeline
// (P0/P1 parity, hand-unrolled so all reg indices are static): loads are issued
// ~2 iterations (~700 cyc) before their MFMA, covering L3 latency (fn+nn = 6 MB
// > 4 MB L2/XCD; r10 counters: 1-deep prefetch left 40% stall).
__global__ __launch_bounds__(256, 2) void k_passA(const ushort_t* __restrict__ fnb,
                                                  const ushort_t* __restrict__ nnb,
                                                  float* __restrict__ m1p, float* __restrict__ S1p,
                                                  float* __restrict__ m2p, float* __restrict__ S2p) {
  const int tid  = threadIdx.x;
  const int head = blockIdx.x & 7;
  const int rbk  = (blockIdx.x >> 3) & 7;
  const int js   = blockIdx.x >> 6;
  const int w = tid >> 6, lane = tid & 63, lg = lane >> 4, ln = lane & 15;
  const ushort_t* fh = fnb + head * (NROWS * 64);
  const ushort_t* nh = nnb + head * (MROWS * 64);
  const int base = rbk * 256 + w * 64;
  const int off  = head * 16 + js;
  const int j0 = js * 128;    // 8 f-tiles of 16 rows
  const int t0 = js * 256;    // 16 n-tiles of 16 rows

  bf16x8 a0[4], a1[4];
#pragma unroll
  for (int rs = 0; rs < 4; ++rs) {
    const ushort_t* ap = fh + (base + rs * 16 + ln) * 64 + lg * 8;
    a0[rs] = ldb(ap); a1[rs] = ldb(ap + 32);
  }
  float mc[4][4], sa[4][4];
#pragma unroll
  for (int rs = 0; rs < 4; ++rs)
#pragma unroll
    for (int q = 0; q < 4; ++q) { mc[rs][q] = -3.0e38f; sa[rs][q] = 0.0f; }

  // tile tt in [0,24): tt<8 -> f-tile (j0 + tt*16), else n-tile (t0 + (tt-8)*16)
#define TPTR(tt) ((tt) < 8 ? fh + (j0 + (tt) * 16 + ln) * 64 : nh + (t0 + ((tt) - 8) * 16 + ln) * 64)

  // MFMA + online softmax for one 16-col tile held in (Pa,Pb); SELF: exclude diag from sum
#define STEP(Pa, Pb, gjb, SELF)                                                              \
  {                                                                                          \
    _Pragma("unroll") for (int rs = 0; rs < 4; ++rs) {                                       \
      f32x4 c = {0.0f, 0.0f, 0.0f, 0.0f};                                                    \
      c = __builtin_amdgcn_mfma_f32_16x16x32_bf16(a0[rs], __builtin_bit_cast(bf16x8, Pa), c, 0, 0, 0); \
      c = __builtin_amdgcn_mfma_f32_16x16x32_bf16(a1[rs], __builtin_bit_cast(bf16x8, Pb), c, 0, 0, 0); \
      _Pragma("unroll") for (int q = 0; q < 4; ++q) {                                        \
        const float cv = c[q];                                                               \
        mc[rs][q] = fmaxf(mc[rs][q], cv);                                                    \
        float e = exp2f(fmaf(cv, K2, -K2));                                                  \
        if (SELF && (base + rs * 16 + lg * 4 + q == (gjb) + ln)) e = 0.0f;                   \
        sa[rs][q] += e;                                                                      \
      }                                                                                      \
    }                                                                                        \
  }

  // prologue: tiles 0,1 in flight
  const ushort_t* p0 = TPTR(0);
  uint4 P0a = *(const uint4*)(p0 + lg * 8), P0b = *(const uint4*)(p0 + 32 + lg * 8);
  const ushort_t* p1 = TPTR(1);
  uint4 P1a = *(const uint4*)(p1 + lg * 8), P1b = *(const uint4*)(p1 + 32 + lg * 8);

  // loop A: f-tiles 0..7 (prefetch runs ahead into n-tiles 8,9)
  for (int ji = 0; ji < 8; ji += 2) {
    {
      const ushort_t* np = TPTR(ji + 2);
      const uint4 na = *(const uint4*)(np + lg * 8), nb = *(const uint4*)(np + 32 + lg * 8);
      STEP(P0a, P0b, j0 + ji * 16, 1);
      P0a = na; P0b = nb;
    }
    {
      const ushort_t* np = TPTR(ji + 3);
      const uint4 na = *(const uint4*)(np + lg * 8), nb = *(const uint4*)(np + 32 + lg * 8);
      STEP(P1a, P1b, j0 + (ji + 1) * 16, 1);
      P1a = na; P1b = nb;
    }
  }
  store_ms4(mc, sa, m1p, S1p, base, off, lg, ln);

  // loop B: n-tiles 8..23 (tail prefetch clamped to tile 23; harmless reload)
  for (int k = 0; k < 16; k += 2) {
    {
      const int tn = (k + 10 < 24) ? k + 10 : 23;
      const ushort_t* np = TPTR(tn);
      const uint4 na = *(const uint4*)(np + lg * 8), nb = *(const uint4*)(np + 32 + lg * 8);
      STEP(P0a, P0b, 0, 0);
      P0a = na; P0b = nb;
    }
    {
      const int tn = (k + 11 < 24) ? k + 11 : 23;
      const ushort_t* np = TPTR(tn);
      const uint4 na = *(const uint4*)(np + lg * 8), nb = *(const uint4*)(np + 32 + lg * 8);
      STEP(P1a, P1b, 0, 0);
      P1a = na; P1b = nb;
    }
  }
  store_ms4(mc, sa, m2p, S2p, base, off, lg, ln);
#undef STEP
#undef TPTR
}

// k_denom: merge the 16 j-split partials once per (row, head) -> dnm[row*8+h].
// Previously every passB block re-merged its i-tile's partials (32x redundant).
__global__ void k_denom(const float* __restrict__ m1p, const float* __restrict__ S1p,
                        const float* __restrict__ m2p, const float* __restrict__ S2p,
                        float* __restrict__ dnm) {
  const int e = blockIdx.x * 256 + threadIdx.x;   // 16384 = 2048 rows x 8 heads
  const int row = e >> 3, h = e & 7;
  const int bidx = row * 128 + h * 16;
  float4 mq[4], sq[4], m2q[4], s2q[4];
#pragma unroll
  for (int k = 0; k < 4; ++k) {
    mq[k]  = *(const float4*)(m1p + bidx + 4 * k);
    sq[k]  = *(const float4*)(S1p + bidx + 4 * k);
    m2q[k] = *(const float4*)(m2p + bidx + 4 * k);
    s2q[k] = *(const float4*)(S2p + bidx + 4 * k);
  }
  float m = -3.0e38f, m2 = -3.0e38f;
#pragma unroll
  for (int k = 0; k < 4; ++k) {
    m  = fmaxf(m,  fmaxf(fmaxf(mq[k].x,  mq[k].y),  fmaxf(mq[k].z,  mq[k].w)));
    m2 = fmaxf(m2, fmaxf(fmaxf(m2q[k].x, m2q[k].y), fmaxf(m2q[k].z, m2q[k].w)));
  }
  float s = 0.0f, s2 = 0.0f;
#pragma unroll
  for (int k = 0; k < 4; ++k) {
    s  += sq[k].x  * __expf(mq[k].x  - m)  + sq[k].y  * __expf(mq[k].y  - m)
        + sq[k].z  * __expf(mq[k].z  - m)  + sq[k].w  * __expf(mq[k].w  - m);
    s2 += s2q[k].x * __expf(m2q[k].x - m2) + s2q[k].y * __expf(m2q[k].y - m2)
        + s2q[k].z * __expf(m2q[k].z - m2) + s2q[k].w * __expf(m2q[k].w - m2);
  }
  dnm[row * 8 + h] = m + __logf(s + s2);   // reference's mixed-max denom
}

// pass B: per (i,j) max-over-heads with bestdn tracked in regs; masked accumulation.
// grid: 1024 = i-tile(32) x j-tile(32); wave owns 16 i-rows x 64 j-cols.
__global__ __launch_bounds__(256, 2) void k_passB(const ushort_t* __restrict__ fnb,
                                                  const float* __restrict__ dnm,
                                                  const u64* __restrict__ lbits,
                                                  float* __restrict__ rowsum, float* __restrict__ rowcnt) {
  __shared__ float dn[64 * 9];
  const int tid = threadIdx.x;
  const int it = blockIdx.x >> 5, jt = blockIdx.x & 31;
  const int ibase = it * 64, jbase = jt * 64;
  const int w = tid >> 6, lane = tid & 63, lg = lane >> 4, ln = lane & 15;

  // stage this i-tile's denom rows (coalesced 512-float read)
  for (int e = tid; e < 512; e += 256) {
    const int il = e >> 3, h = e & 7;
    dn[il * 9 + h] = dnm[(ibase + il) * 8 + h];
  }
  __syncthreads();

  // per-lane copy of denom for its 4 i-rows (statically indexed in the h-unroll)
  float dnr[4][8];
#pragma unroll
  for (int q = 0; q < 4; ++q) {
    const int il = w * 16 + lg * 4 + q;
#pragma unroll
    for (int h = 0; h < 8; ++h) dnr[q][h] = dn[il * 9 + h];
  }

  const int irow = ibase + w * 16 + ln;
  float maxd[4][4], bestdn[4][4];
#pragma unroll
  for (int sj = 0; sj < 4; ++sj)
#pragma unroll
    for (int q = 0; q < 4; ++q) { maxd[sj][q] = -3.0e38f; bestdn[sj][q] = 0.0f; }

#pragma unroll
  for (int h = 0; h < 8; ++h) {
    const ushort_t* fh = fnb + h * (NROWS * 64);
    const bf16x8 a0 = ldb(fh + irow * 64 + lg * 8);
    const bf16x8 a1 = ldb(fh + irow * 64 + 32 + lg * 8);
#pragma unroll
    for (int sj = 0; sj < 4; ++sj) {
      const int jrow = jbase + sj * 16 + ln;
      const bf16x8 b0 = ldb(fh + jrow * 64 + lg * 8);
      const bf16x8 b1 = ldb(fh + jrow * 64 + 32 + lg * 8);
      f32x4 c = {0.0f, 0.0f, 0.0f, 0.0f};
      c = __builtin_amdgcn_mfma_f32_16x16x32_bf16(a0, b0, c, 0, 0, 0);
      c = __builtin_amdgcn_mfma_f32_16x16x32_bf16(a1, b1, c, 0, 0, 0);
#pragma unroll
      for (int q = 0; q < 4; ++q)
        if (c[q] > maxd[sj][q]) { maxd[sj][q] = c[q]; bestdn[sj][q] = dnr[q][h]; }  // first-max tiebreak
    }
  }

  u64 lbi[4];
#pragma unroll
  for (int q = 0; q < 4; ++q) lbi[q] = lbits[(ibase + w * 16 + lg * 4 + q) & (BLAB - 1)];
  float rs[4] = {0, 0, 0, 0}, rc[4] = {0, 0, 0, 0};
#pragma unroll
  for (int sj = 0; sj < 4; ++sj) {
    const int gj = jbase + sj * 16 + ln;
    const u64 lbj = lbits[gj & (BLAB - 1)];
#pragma unroll
    for (int q = 0; q < 4; ++q) {
      const int gi = ibase + w * 16 + lg * 4 + q;
      if (gi != gj && (lbi[q] & lbj)) {
        rs[q] += maxd[sj][q] * INVT - bestdn[sj][q];
        rc[q] += 1.0f;
      }
    }
  }
#pragma unroll
  for (int q = 0; q < 4; ++q) {
#pragma unroll
    for (int d = 1; d < 16; d <<= 1) {
      rs[q] += __shfl_xor(rs[q], d, 64);
      rc[q] += __shfl_xor(rc[q], d, 64);
    }
  }
  if (ln == 0) {
#pragma unroll
    for (int q = 0; q < 4; ++q) {
      const int row = ibase + w * 16 + lg * 4 + q;
      atomicAdd(&rowsum[row], rs[q]);
      atomicAdd(&rowcnt[row], rc[q]);
    }
  }
}

// final: mean over rows with cnt>0 of -(rowsum/cnt); empty -> 0
__global__ void k_final(const float* __restrict__ rowsum, const float* __restrict__ rowcnt,
                        float* __restrict__ out) {
  __shared__ float sdata[4][2];
  const int tid = threadIdx.x;
  float s = 0.0f, c = 0.0f;
  for (int i = tid; i < NROWS; i += 256) {
    const float cnt = rowcnt[i];
    if (cnt > 0.0f) { s -= rowsum[i] / cnt; c += 1.0f; }
  }
#pragma unroll
  for (int d = 32; d; d >>= 1) { s += __shfl_xor(s, d, 64); c += __shfl_xor(c, d, 64); }
  const int w = tid >> 6;
  if ((tid & 63) == 0) { sdata[w][0] = s; sdata[w][1] = c; }
  __syncthreads();
  if (tid == 0) {
    s = 0.0f; c = 0.0f;
#pragma unroll
    for (int w2 = 0; w2 < 4; ++w2) { s += sdata[w2][0]; c += sdata[w2][1]; }
    out[0] = (c > 0.0f) ? s / c : 0.0f;
  }
}

extern "C" void kernel_launch(void* const* d_in, const int* in_sizes, int n_in,
                              void* d_out, int out_size, void* d_ws, size_t ws_size,
                              hipStream_t stream) {
  const float* feat   = (const float*)d_in[0];
  const float* negs   = (const float*)d_in[1];
  const float* labels = (const float*)d_in[2];
  float* out = (float*)d_out;

  ushort_t* fnb = (ushort_t*)d_ws;              // (H,N,64) bf16 = 2 MB
  ushort_t* nnb = fnb + 8 * NROWS * 64;         // (H,M,64) bf16 = 4 MB
  float* m1p = (float*)(nnb + 8 * MROWS * 64);  // (N,128) each = 1 MB x 4
  float* S1p = m1p + NROWS * 128;
  float* m2p = S1p + NROWS * 128;
  float* S2p = m2p + NROWS * 128;
  float* rowsum = S2p + NROWS * 128;            // 2048
  float* rowcnt = rowsum + 2048;                // 2048
  u64*   lbits  = (u64*)(rowcnt + 2048);        // 1024
  float* dnm    = (float*)(lbits + 1024);       // (N,8) = 64 KB

  k_prep<<<3328, 256, 0, stream>>>(feat, negs, labels, fnb, nnb, lbits, rowsum);
  k_passA<<<1024, 256, 0, stream>>>(fnb, nnb, m1p, S1p, m2p, S2p);
  k_denom<<<64, 256, 0, stream>>>(m1p, S1p, m2p, S2p, dnm);
  k_passB<<<1024, 256, 0, stream>>>(fnb, dnm, lbits, rowsum, rowcnt);
  k_final<<<1, 256, 0, stream>>>(rowsum, rowcnt, out);
}

// Round 14
// 162.186 us; speedup vs baseline: 3.0178x; 1.0090x over previous
//
#include <hip/hip_runtime.h>

typedef unsigned long long u64;
typedef unsigned short ushort_t;
typedef __bf16 bf16x8 __attribute__((ext_vector_type(8)));
typedef float f32x4 __attribute__((ext_vector_type(4)));

#define NROWS 2048
#define MROWS 4096
#define BLAB  1024
#define INVT  (1.0f / 0.07f)
#define K2    (INVT * 1.4426950408889634f)   // (1/T) * log2(e)

__device__ __forceinline__ bf16x8 ldb(const ushort_t* p) {
  return __builtin_bit_cast(bf16x8, *(const uint4*)p);
}

__device__ __forceinline__ ushort_t f2bf(float f) {
  unsigned u = __float_as_uint(f);
  u += 0x7fff + ((u >> 16) & 1);   // RNE (inputs finite)
  return (ushort_t)(u >> 16);
}

// ---------- k_prep: L2-normalize -> bf16 (blocks < 3072) + label bitmasks/zeroing ----------
__global__ void k_prep(const float* __restrict__ feat, const float* __restrict__ negs,
                       const float* __restrict__ labels,
                       ushort_t* __restrict__ fnb, ushort_t* __restrict__ nnb,
                       u64* __restrict__ lbits, float* __restrict__ zbuf) {
  if (blockIdx.x >= 3072) {
    const int gtid = (blockIdx.x - 3072) * 256 + threadIdx.x;
    if (gtid < 4096) zbuf[gtid] = 0.0f;           // rowsum + rowcnt
    const int wid  = gtid >> 6;
    const int lane = threadIdx.x & 63;
    if (wid < BLAB) {
      float v = labels[wid * 64 + lane];
      u64 msk = __ballot(v != 0.0f);
      if (lane == 0) lbits[wid] = msk;
    }
    return;
  }
  const int wid  = blockIdx.x * 4 + ((threadIdx.x >> 6));
  const int lane = threadIdx.x & 63;
  const int g = lane >> 4, ln = lane & 15;
  const int p = wid * 4 + g;                      // (row,head) pair index
  const float* src;
  ushort_t* dst;
  if (p < NROWS * 8) {
    const int i = p >> 3, h = p & 7;
    const int b = i & (BLAB - 1), v = i >> 10;    // i = v*B + b (view-major concat)
    src = feat + (b * 2 + v) * 512 + h * 64;
    dst = fnb + (h * NROWS + i) * 64;
  } else {
    const int q = p - NROWS * 8;
    const int m = q >> 3, h = q & 7;
    const int b2 = m & 2047, v = m >> 11;         // m = v*B2 + b2
    src = negs + (b2 * 2 + v) * 512 + h * 64;
    dst = nnb + (h * MROWS + m) * 64;
  }
  const float4 x = *(const float4*)(src + 4 * ln);
  float ss = x.x * x.x + x.y * x.y + x.z * x.z + x.w * x.w;
#pragma unroll
  for (int d = 1; d < 16; d <<= 1) ss += __shfl_xor(ss, d, 64);
  const float inv = 1.0f / fmaxf(sqrtf(ss), 1e-12f);
  ushort4 o;
  o.x = f2bf(x.x * inv); o.y = f2bf(x.y * inv);
  o.z = f2bf(x.z * inv); o.w = f2bf(x.w * inv);
  *(ushort4*)(dst + 4 * ln) = o;
}

// reduce (max, sum) over the ln dimension; store reference-framed (m, S); reset accums
__device__ __forceinline__ void store_ms4(float mc[4][4], float sa[4][4],
                                          float* __restrict__ gm, float* __restrict__ gs,
                                          int base, int off, int lg, int ln) {
#pragma unroll
  for (int rs = 0; rs < 4; ++rs) {
#pragma unroll
    for (int q = 0; q < 4; ++q) {
      float m = mc[rs][q], s = sa[rs][q];
#pragma unroll
      for (int d = 1; d < 16; d <<= 1) {
        m = fmaxf(m, __shfl_xor(m, d, 64));
        s += __shfl_xor(s, d, 64);
      }
      if (ln == 0) {
        const int row = base + rs * 16 + lg * 4 + q;
        gm[row * 128 + off] = m * INVT;                 // m = max(sim)/T
        gs[row * 128 + off] = s * exp2f((1.0f - m) * K2); // S = sum exp(x - m)
      }
      mc[rs][q] = -3.0e38f; sa[rs][q] = 0.0f;
    }
  }
}

// pass A: online max + sum-exp over j (self excluded from sum only) and over m.
// Wave owns 64 i-rows (4 A-frag pairs in regs). Flat stream of 24 B-tiles
// (8 f-tiles then 16 n-tiles) through a DEPTH-4 register pipeline P0..P3:
// consume-then-refill with full static naming, so each tile's load has ~3 STEPs
// (~750 cyc) to complete -- covering L3 latency (fn+nn = 6 MB > 4 MB L2/XCD).
// r13: depth-2 gave only 60.6->55.6 since coverage (~500 cyc) < latency.
__global__ __launch_bounds__(256, 2) void k_passA(const ushort_t* __restrict__ fnb,
                                                  const ushort_t* __restrict__ nnb,
                                                  float* __restrict__ m1p, float* __restrict__ S1p,
                                                  float* __restrict__ m2p, float* __restrict__ S2p) {
  const int tid  = threadIdx.x;
  const int head = blockIdx.x & 7;
  const int rbk  = (blockIdx.x >> 3) & 7;
  const int js   = blockIdx.x >> 6;
  const int w = tid >> 6, lane = tid & 63, lg = lane >> 4, ln = lane & 15;
  const ushort_t* fh = fnb + head * (NROWS * 64);
  const ushort_t* nh = nnb + head * (MROWS * 64);
  const int base = rbk * 256 + w * 64;
  const int off  = head * 16 + js;
  const int j0 = js * 128;    // 8 f-tiles of 16 rows
  const int t0 = js * 256;    // 16 n-tiles of 16 rows

  bf16x8 a0[4], a1[4];
#pragma unroll
  for (int rs = 0; rs < 4; ++rs) {
    const ushort_t* ap = fh + (base + rs * 16 + ln) * 64 + lg * 8;
    a0[rs] = ldb(ap); a1[rs] = ldb(ap + 32);
  }
  float mc[4][4], sa[4][4];
#pragma unroll
  for (int rs = 0; rs < 4; ++rs)
#pragma unroll
    for (int q = 0; q < 4; ++q) { mc[rs][q] = -3.0e38f; sa[rs][q] = 0.0f; }

  // tile tt in [0,24): tt<8 -> f-tile (j0 + tt*16), else n-tile (t0 + (tt-8)*16)
#define TPTR(tt) ((tt) < 8 ? fh + (j0 + (tt) * 16 + ln) * 64 : nh + (t0 + ((tt) - 8) * 16 + ln) * 64)
#define NPTR(tt) (nh + (t0 + ((tt) - 8) * 16 + ln) * 64)
#define LOADT(PA, PB, tt) { const ushort_t* np_ = TPTR(tt); PA = *(const uint4*)(np_ + lg * 8); PB = *(const uint4*)(np_ + 32 + lg * 8); }
#define LOADN(PA, PB, tt) { const ushort_t* np_ = NPTR(tt); PA = *(const uint4*)(np_ + lg * 8); PB = *(const uint4*)(np_ + 32 + lg * 8); }

  // MFMA + online softmax for one 16-col tile held in (Pa,Pb); SELF: exclude diag from sum
#define STEP(Pa, Pb, gjb, SELF)                                                              \
  {                                                                                          \
    _Pragma("unroll") for (int rs = 0; rs < 4; ++rs) {                                       \
      f32x4 c = {0.0f, 0.0f, 0.0f, 0.0f};                                                    \
      c = __builtin_amdgcn_mfma_f32_16x16x32_bf16(a0[rs], __builtin_bit_cast(bf16x8, Pa), c, 0, 0, 0); \
      c = __builtin_amdgcn_mfma_f32_16x16x32_bf16(a1[rs], __builtin_bit_cast(bf16x8, Pb), c, 0, 0, 0); \
      _Pragma("unroll") for (int q = 0; q < 4; ++q) {                                        \
        const float cv = c[q];                                                               \
        mc[rs][q] = fmaxf(mc[rs][q], cv);                                                    \
        float e = exp2f(fmaf(cv, K2, -K2));                                                  \
        if (SELF && (base + rs * 16 + lg * 4 + q == (gjb) + ln)) e = 0.0f;                   \
        sa[rs][q] += e;                                                                      \
      }                                                                                      \
    }                                                                                        \
  }

  // prologue: tiles 0..3 in flight
  uint4 P0a, P0b, P1a, P1b, P2a, P2b, P3a, P3b;
  LOADT(P0a, P0b, 0); LOADT(P1a, P1b, 1); LOADT(P2a, P2b, 2); LOADT(P3a, P3b, 3);

  // loop A: f-tiles 0..7 with SELF; prefetch crosses into n-tiles (TPTR ternary)
#pragma unroll 1
  for (int jj = 0; jj < 8; jj += 4) {
    STEP(P0a, P0b, j0 + jj * 16, 1);        LOADT(P0a, P0b, jj + 4);
    STEP(P1a, P1b, j0 + (jj + 1) * 16, 1);  LOADT(P1a, P1b, jj + 5);
    STEP(P2a, P2b, j0 + (jj + 2) * 16, 1);  LOADT(P2a, P2b, jj + 6);
    STEP(P3a, P3b, j0 + (jj + 3) * 16, 1);  LOADT(P3a, P3b, jj + 7);
  }
  store_ms4(mc, sa, m1p, S1p, base, off, lg, ln);   // tiles 0-7 consumed; 8-11 in flight

  // loop B: n-tiles 8..23; last group peeled (no dead prefetch)
#pragma unroll 1
  for (int kk = 8; kk < 20; kk += 4) {
    STEP(P0a, P0b, 0, 0);  LOADN(P0a, P0b, kk + 4);
    STEP(P1a, P1b, 0, 0);  LOADN(P1a, P1b, kk + 5);
    STEP(P2a, P2b, 0, 0);  LOADN(P2a, P2b, kk + 6);
    STEP(P3a, P3b, 0, 0);  LOADN(P3a, P3b, kk + 7);
  }
  STEP(P0a, P0b, 0, 0);
  STEP(P1a, P1b, 0, 0);
  STEP(P2a, P2b, 0, 0);
  STEP(P3a, P3b, 0, 0);
  store_ms4(mc, sa, m2p, S2p, base, off, lg, ln);
#undef STEP
#undef LOADT
#undef LOADN
#undef TPTR
#undef NPTR
}

// k_denom: merge the 16 j-split partials once per (row, head) -> dnm[row*8+h].
__global__ void k_denom(const float* __restrict__ m1p, const float* __restrict__ S1p,
                        const float* __restrict__ m2p, const float* __restrict__ S2p,
                        float* __restrict__ dnm) {
  const int e = blockIdx.x * 256 + threadIdx.x;   // 16384 = 2048 rows x 8 heads
  const int row = e >> 3, h = e & 7;
  const int bidx = row * 128 + h * 16;
  float4 mq[4], sq[4], m2q[4], s2q[4];
#pragma unroll
  for (int k = 0; k < 4; ++k) {
    mq[k]  = *(const float4*)(m1p + bidx + 4 * k);
    sq[k]  = *(const float4*)(S1p + bidx + 4 * k);
    m2q[k] = *(const float4*)(m2p + bidx + 4 * k);
    s2q[k] = *(const float4*)(S2p + bidx + 4 * k);
  }
  float m = -3.0e38f, m2 = -3.0e38f;
#pragma unroll
  for (int k = 0; k < 4; ++k) {
    m  = fmaxf(m,  fmaxf(fmaxf(mq[k].x,  mq[k].y),  fmaxf(mq[k].z,  mq[k].w)));
    m2 = fmaxf(m2, fmaxf(fmaxf(m2q[k].x, m2q[k].y), fmaxf(m2q[k].z, m2q[k].w)));
  }
  float s = 0.0f, s2 = 0.0f;
#pragma unroll
  for (int k = 0; k < 4; ++k) {
    s  += sq[k].x  * __expf(mq[k].x  - m)  + sq[k].y  * __expf(mq[k].y  - m)
        + sq[k].z  * __expf(mq[k].z  - m)  + sq[k].w  * __expf(mq[k].w  - m);
    s2 += s2q[k].x * __expf(m2q[k].x - m2) + s2q[k].y * __expf(m2q[k].y - m2)
        + s2q[k].z * __expf(m2q[k].z - m2) + s2q[k].w * __expf(m2q[k].w - m2);
  }
  dnm[row * 8 + h] = m + __logf(s + s2);   // reference's mixed-max denom
}

// pass B: per (i,j) max-over-heads with bestdn tracked in regs; masked accumulation.
// grid: 1024 = i-tile(32) x j-tile(32); wave owns 16 i-rows x 64 j-cols.
__global__ __launch_bounds__(256, 2) void k_passB(const ushort_t* __restrict__ fnb,
                                                  const float* __restrict__ dnm,
                                                  const u64* __restrict__ lbits,
                                                  float* __restrict__ rowsum, float* __restrict__ rowcnt) {
  __shared__ float dn[64 * 9];
  const int tid = threadIdx.x;
  const int it = blockIdx.x >> 5, jt = blockIdx.x & 31;
  const int ibase = it * 64, jbase = jt * 64;
  const int w = tid >> 6, lane = tid & 63, lg = lane >> 4, ln = lane & 15;

  // stage this i-tile's denom rows (coalesced 512-float read)
  for (int e = tid; e < 512; e += 256) {
    const int il = e >> 3, h = e & 7;
    dn[il * 9 + h] = dnm[(ibase + il) * 8 + h];
  }
  __syncthreads();

  // per-lane copy of denom for its 4 i-rows (statically indexed in the h-unroll)
  float dnr[4][8];
#pragma unroll
  for (int q = 0; q < 4; ++q) {
    const int il = w * 16 + lg * 4 + q;
#pragma unroll
    for (int h = 0; h < 8; ++h) dnr[q][h] = dn[il * 9 + h];
  }

  const int irow = ibase + w * 16 + ln;
  float maxd[4][4], bestdn[4][4];
#pragma unroll
  for (int sj = 0; sj < 4; ++sj)
#pragma unroll
    for (int q = 0; q < 4; ++q) { maxd[sj][q] = -3.0e38f; bestdn[sj][q] = 0.0f; }

#pragma unroll
  for (int h = 0; h < 8; ++h) {
    const ushort_t* fh = fnb + h * (NROWS * 64);
    const bf16x8 a0 = ldb(fh + irow * 64 + lg * 8);
    const bf16x8 a1 = ldb(fh + irow * 64 + 32 + lg * 8);
#pragma unroll
    for (int sj = 0; sj < 4; ++sj) {
      const int jrow = jbase + sj * 16 + ln;
      const bf16x8 b0 = ldb(fh + jrow * 64 + lg * 8);
      const bf16x8 b1 = ldb(fh + jrow * 64 + 32 + lg * 8);
      f32x4 c = {0.0f, 0.0f, 0.0f, 0.0f};
      c = __builtin_amdgcn_mfma_f32_16x16x32_bf16(a0, b0, c, 0, 0, 0);
      c = __builtin_amdgcn_mfma_f32_16x16x32_bf16(a1, b1, c, 0, 0, 0);
#pragma unroll
      for (int q = 0; q < 4; ++q)
        if (c[q] > maxd[sj][q]) { maxd[sj][q] = c[q]; bestdn[sj][q] = dnr[q][h]; }  // first-max tiebreak
    }
  }

  u64 lbi[4];
#pragma unroll
  for (int q = 0; q < 4; ++q) lbi[q] = lbits[(ibase + w * 16 + lg * 4 + q) & (BLAB - 1)];
  float rs[4] = {0, 0, 0, 0}, rc[4] = {0, 0, 0, 0};
#pragma unroll
  for (int sj = 0; sj < 4; ++sj) {
    const int gj = jbase + sj * 16 + ln;
    const u64 lbj = lbits[gj & (BLAB - 1)];
#pragma unroll
    for (int q = 0; q < 4; ++q) {
      const int gi = ibase + w * 16 + lg * 4 + q;
      if (gi != gj && (lbi[q] & lbj)) {
        rs[q] += maxd[sj][q] * INVT - bestdn[sj][q];
        rc[q] += 1.0f;
      }
    }
  }
#pragma unroll
  for (int q = 0; q < 4; ++q) {
#pragma unroll
    for (int d = 1; d < 16; d <<= 1) {
      rs[q] += __shfl_xor(rs[q], d, 64);
      rc[q] += __shfl_xor(rc[q], d, 64);
    }
  }
  if (ln == 0) {
#pragma unroll
    for (int q = 0; q < 4; ++q) {
      const int row = ibase + w * 16 + lg * 4 + q;
      atomicAdd(&rowsum[row], rs[q]);
      atomicAdd(&rowcnt[row], rc[q]);
    }
  }
}

// final: mean over rows with cnt>0 of -(rowsum/cnt); empty -> 0
__global__ void k_final(const float* __restrict__ rowsum, const float* __restrict__ rowcnt,
                        float* __restrict__ out) {
  __shared__ float sdata[4][2];
  const int tid = threadIdx.x;
  float s = 0.0f, c = 0.0f;
  for (int i = tid; i < NROWS; i += 256) {
    const float cnt = rowcnt[i];
    if (cnt > 0.0f) { s -= rowsum[i] / cnt; c += 1.0f; }
  }
#pragma unroll
  for (int d = 32; d; d >>= 1) { s += __shfl_xor(s, d, 64); c += __shfl_xor(c, d, 64); }
  const int w = tid >> 6;
  if ((tid & 63) == 0) { sdata[w][0] = s; sdata[w][1] = c; }
  __syncthreads();
  if (tid == 0) {
    s = 0.0f; c = 0.0f;
#pragma unroll
    for (int w2 = 0; w2 < 4; ++w2) { s += sdata[w2][0]; c += sdata[w2][1]; }
    out[0] = (c > 0.0f) ? s / c : 0.0f;
  }
}

extern "C" void kernel_launch(void* const* d_in, const int* in_sizes, int n_in,
                              void* d_out, int out_size, void* d_ws, size_t ws_size,
                              hipStream_t stream) {
  const float* feat   = (const float*)d_in[0];
  const float* negs   = (const float*)d_in[1];
  const float* labels = (const float*)d_in[2];
  float* out = (float*)d_out;

  ushort_t* fnb = (ushort_t*)d_ws;              // (H,N,64) bf16 = 2 MB
  ushort_t* nnb = fnb + 8 * NROWS * 64;         // (H,M,64) bf16 = 4 MB
  float* m1p = (float*)(nnb + 8 * MROWS * 64);  // (N,128) each = 1 MB x 4
  float* S1p = m1p + NROWS * 128;
  float* m2p = S1p + NROWS * 128;
  float* S2p = m2p + NROWS * 128;
  float* rowsum = S2p + NROWS * 128;            // 2048
  float* rowcnt = rowsum + 2048;                // 2048
  u64*   lbits  = (u64*)(rowcnt + 2048);        // 1024
  float* dnm    = (float*)(lbits + 1024);       // (N,8) = 64 KB

  k_prep<<<3328, 256, 0, stream>>>(feat, negs, labels, fnb, nnb, lbits, rowsum);
  k_passA<<<1024, 256, 0, stream>>>(fnb, nnb, m1p, S1p, m2p, S2p);
  k_denom<<<64, 256, 0, stream>>>(m1p, S1p, m2p, S2p, dnm);
  k_passB<<<1024, 256, 0, stream>>>(fnb, dnm, lbits, rowsum, rowcnt);
  k_final<<<1, 256, 0, stream>>>(rowsum, rowcnt, out);
}

// Round 15
// 159.870 us; speedup vs baseline: 3.0615x; 1.0145x over previous
//
#include <hip/hip_runtime.h>

typedef unsigned long long u64;
typedef unsigned short ushort_t;
typedef __bf16 bf16x8 __attribute__((ext_vector_type(8)));
typedef float f32x4 __attribute__((ext_vector_type(4)));

#define NROWS 2048
#define MROWS 4096
#define BLAB  1024
#define INVT  (1.0f / 0.07f)
#define K2    (INVT * 1.4426950408889634f)   // (1/T) * log2(e)

__device__ __forceinline__ bf16x8 ldb(const ushort_t* p) {
  return __builtin_bit_cast(bf16x8, *(const uint4*)p);
}

__device__ __forceinline__ ushort_t f2bf(float f) {
  unsigned u = __float_as_uint(f);
  u += 0x7fff + ((u >> 16) & 1);   // RNE (inputs finite)
  return (ushort_t)(u >> 16);
}

// ---------- k_prep: L2-normalize -> bf16 (blocks < 3072) + label bitmasks/zeroing ----------
__global__ void k_prep(const float* __restrict__ feat, const float* __restrict__ negs,
                       const float* __restrict__ labels,
                       ushort_t* __restrict__ fnb, ushort_t* __restrict__ nnb,
                       u64* __restrict__ lbits, float* __restrict__ zbuf) {
  if (blockIdx.x >= 3072) {
    const int gtid = (blockIdx.x - 3072) * 256 + threadIdx.x;
    if (gtid < 4096) zbuf[gtid] = 0.0f;           // rowsum + rowcnt
    const int wid  = gtid >> 6;
    const int lane = threadIdx.x & 63;
    if (wid < BLAB) {
      float v = labels[wid * 64 + lane];
      u64 msk = __ballot(v != 0.0f);
      if (lane == 0) lbits[wid] = msk;
    }
    return;
  }
  const int wid  = blockIdx.x * 4 + ((threadIdx.x >> 6));
  const int lane = threadIdx.x & 63;
  const int g = lane >> 4, ln = lane & 15;
  const int p = wid * 4 + g;                      // (row,head) pair index
  const float* src;
  ushort_t* dst;
  if (p < NROWS * 8) {
    const int i = p >> 3, h = p & 7;
    const int b = i & (BLAB - 1), v = i >> 10;    // i = v*B + b (view-major concat)
    src = feat + (b * 2 + v) * 512 + h * 64;
    dst = fnb + (h * NROWS + i) * 64;
  } else {
    const int q = p - NROWS * 8;
    const int m = q >> 3, h = q & 7;
    const int b2 = m & 2047, v = m >> 11;         // m = v*B2 + b2
    src = negs + (b2 * 2 + v) * 512 + h * 64;
    dst = nnb + (h * MROWS + m) * 64;
  }
  const float4 x = *(const float4*)(src + 4 * ln);
  float ss = x.x * x.x + x.y * x.y + x.z * x.z + x.w * x.w;
#pragma unroll
  for (int d = 1; d < 16; d <<= 1) ss += __shfl_xor(ss, d, 64);
  const float inv = 1.0f / fmaxf(sqrtf(ss), 1e-12f);
  ushort4 o;
  o.x = f2bf(x.x * inv); o.y = f2bf(x.y * inv);
  o.z = f2bf(x.z * inv); o.w = f2bf(x.w * inv);
  *(ushort4*)(dst + 4 * ln) = o;
}

// reduce (max, sum) over the ln dimension; store reference-framed (m, S); reset accums
__device__ __forceinline__ void store_ms4(float mc[4][4], float sa[4][4],
                                          float* __restrict__ gm, float* __restrict__ gs,
                                          int base, int off, int lg, int ln) {
#pragma unroll
  for (int rs = 0; rs < 4; ++rs) {
#pragma unroll
    for (int q = 0; q < 4; ++q) {
      float m = mc[rs][q], s = sa[rs][q];
#pragma unroll
      for (int d = 1; d < 16; d <<= 1) {
        m = fmaxf(m, __shfl_xor(m, d, 64));
        s += __shfl_xor(s, d, 64);
      }
      if (ln == 0) {
        const int row = base + rs * 16 + lg * 4 + q;
        gm[row * 128 + off] = m * INVT;                 // m = max(sim)/T
        gs[row * 128 + off] = s * exp2f((1.0f - m) * K2); // S = sum exp(x - m)
      }
      mc[rs][q] = -3.0e38f; sa[rs][q] = 0.0f;
    }
  }
}

// pass A: online max + sum-exp over j (self excluded from sum only) and over m.
// Wave owns 64 i-rows (4 A-frag pairs in regs). The block's whole 24-tile B-stream
// (48 KB) is staged ONCE into LDS via global_load_lds(16B) -- 12 rounds, one
// vmcnt(0)+barrier -- then all 4 waves compute from LDS with no further syncs.
// r13/r14 lesson: per-wave register prefetch (depth 2,4) couldn't cover the
// L3-class stream latency (52-56us); one fetch per block + LDS-latency reads
// removes the per-wave exposure entirely. Bank fix: global source chunk order
// pre-swizzled (chunk ^= row&7, LDS dest stays linear per m173); reads use the
// matching XOR -> ~2-way conflicts (free).
__global__ __launch_bounds__(256, 2) void k_passA(const ushort_t* __restrict__ fnb,
                                                  const ushort_t* __restrict__ nnb,
                                                  float* __restrict__ m1p, float* __restrict__ S1p,
                                                  float* __restrict__ m2p, float* __restrict__ S2p) {
  __shared__ ushort_t Bs[24 * 1024];   // 24 tiles x (16 rows x 64 bf16), chunk-swizzled
  const int tid  = threadIdx.x;
  const int head = blockIdx.x & 7;
  const int rbk  = (blockIdx.x >> 3) & 7;
  const int js   = blockIdx.x >> 6;
  const int w = tid >> 6, lane = tid & 63, lg = lane >> 4, ln = lane & 15;
  const ushort_t* fh = fnb + head * (NROWS * 64);
  const ushort_t* nh = nnb + head * (MROWS * 64);
  const int base = rbk * 256 + w * 64;
  const int off  = head * 16 + js;
  const int j0 = js * 128;    // 8 f-tiles of 16 rows
  const int t0 = js * 256;    // 16 n-tiles of 16 rows

  // ---- stage 24 tiles: thread t covers (tile = 2r + t/128, pos = t%128) ----
  // pos = row*8 + k; LDS pos holds global chunk (k ^ (row&7)) of that row.
  {
    const int pos  = tid & 127;
    const int srow = pos >> 3;
    const int sk   = pos & 7;
    const int gsw  = (sk ^ (srow & 7)) * 8;      // swizzled chunk -> ushort offset
    for (int r = 0; r < 12; ++r) {
      const int tl = r * 2 + (tid >> 7);
      const ushort_t* gsrc = (tl < 8 ? fh + (j0 + tl * 16 + srow) * 64
                                     : nh + (t0 + (tl - 8) * 16 + srow) * 64) + gsw;
      __builtin_amdgcn_global_load_lds((const unsigned int*)gsrc,
                                       (unsigned int*)(Bs + tl * 1024 + pos * 8), 16, 0, 0);
    }
  }

  bf16x8 a0[4], a1[4];
#pragma unroll
  for (int rs = 0; rs < 4; ++rs) {
    const ushort_t* ap = fh + (base + rs * 16 + ln) * 64 + lg * 8;
    a0[rs] = ldb(ap); a1[rs] = ldb(ap + 32);
  }
  float mc[4][4], sa[4][4];
#pragma unroll
  for (int rs = 0; rs < 4; ++rs)
#pragma unroll
    for (int q = 0; q < 4; ++q) { mc[rs][q] = -3.0e38f; sa[rs][q] = 0.0f; }

  asm volatile("s_waitcnt vmcnt(0)" ::: "memory");
  __syncthreads();   // staging complete; LDS read-only hereafter (no more barriers)

  // lane (lg,ln) reads tile chunks (row=ln, c=lg) and (row=ln, c=lg+4)
#define TCHUNK(tt, c) (Bs + (tt) * 1024 + (ln * 8 + ((c) ^ (ln & 7))) * 8)
#define STEP(tt, gjb, SELF)                                                                  \
  {                                                                                          \
    const uint4 Pa = *(const uint4*)TCHUNK(tt, lg);                                          \
    const uint4 Pb = *(const uint4*)TCHUNK(tt, lg + 4);                                      \
    _Pragma("unroll") for (int rs = 0; rs < 4; ++rs) {                                       \
      f32x4 c = {0.0f, 0.0f, 0.0f, 0.0f};                                                    \
      c = __builtin_amdgcn_mfma_f32_16x16x32_bf16(a0[rs], __builtin_bit_cast(bf16x8, Pa), c, 0, 0, 0); \
      c = __builtin_amdgcn_mfma_f32_16x16x32_bf16(a1[rs], __builtin_bit_cast(bf16x8, Pb), c, 0, 0, 0); \
      _Pragma("unroll") for (int q = 0; q < 4; ++q) {                                        \
        const float cv = c[q];                                                               \
        mc[rs][q] = fmaxf(mc[rs][q], cv);                                                    \
        float e = exp2f(fmaf(cv, K2, -K2));                                                  \
        if (SELF && (base + rs * 16 + lg * 4 + q == (gjb) + ln)) e = 0.0f;                   \
        sa[rs][q] += e;                                                                      \
      }                                                                                      \
    }                                                                                        \
  }

  // f-tiles 0..7 (self-aware) -> m1/S1
#pragma unroll 2
  for (int tt = 0; tt < 8; ++tt) STEP(tt, j0 + tt * 16, 1);
  store_ms4(mc, sa, m1p, S1p, base, off, lg, ln);

  // n-tiles 8..23 -> m2/S2
#pragma unroll 4
  for (int tt = 8; tt < 24; ++tt) STEP(tt, 0, 0);
  store_ms4(mc, sa, m2p, S2p, base, off, lg, ln);
#undef STEP
#undef TCHUNK
}

// k_denom: merge the 16 j-split partials once per (row, head) -> dnm[row*8+h].
__global__ void k_denom(const float* __restrict__ m1p, const float* __restrict__ S1p,
                        const float* __restrict__ m2p, const float* __restrict__ S2p,
                        float* __restrict__ dnm) {
  const int e = blockIdx.x * 256 + threadIdx.x;   // 16384 = 2048 rows x 8 heads
  const int row = e >> 3, h = e & 7;
  const int bidx = row * 128 + h * 16;
  float4 mq[4], sq[4], m2q[4], s2q[4];
#pragma unroll
  for (int k = 0; k < 4; ++k) {
    mq[k]  = *(const float4*)(m1p + bidx + 4 * k);
    sq[k]  = *(const float4*)(S1p + bidx + 4 * k);
    m2q[k] = *(const float4*)(m2p + bidx + 4 * k);
    s2q[k] = *(const float4*)(S2p + bidx + 4 * k);
  }
  float m = -3.0e38f, m2 = -3.0e38f;
#pragma unroll
  for (int k = 0; k < 4; ++k) {
    m  = fmaxf(m,  fmaxf(fmaxf(mq[k].x,  mq[k].y),  fmaxf(mq[k].z,  mq[k].w)));
    m2 = fmaxf(m2, fmaxf(fmaxf(m2q[k].x, m2q[k].y), fmaxf(m2q[k].z, m2q[k].w)));
  }
  float s = 0.0f, s2 = 0.0f;
#pragma unroll
  for (int k = 0; k < 4; ++k) {
    s  += sq[k].x  * __expf(mq[k].x  - m)  + sq[k].y  * __expf(mq[k].y  - m)
        + sq[k].z  * __expf(mq[k].z  - m)  + sq[k].w  * __expf(mq[k].w  - m);
    s2 += s2q[k].x * __expf(m2q[k].x - m2) + s2q[k].y * __expf(m2q[k].y - m2)
        + s2q[k].z * __expf(m2q[k].z - m2) + s2q[k].w * __expf(m2q[k].w - m2);
  }
  dnm[row * 8 + h] = m + __logf(s + s2);   // reference's mixed-max denom
}

// pass B: per (i,j) max-over-heads with bestdn tracked in regs; masked accumulation.
// grid: 1024 = i-tile(32) x j-tile(32); wave owns 16 i-rows x 64 j-cols.
__global__ __launch_bounds__(256, 2) void k_passB(const ushort_t* __restrict__ fnb,
                                                  const float* __restrict__ dnm,
                                                  const u64* __restrict__ lbits,
                                                  float* __restrict__ rowsum, float* __restrict__ rowcnt) {
  __shared__ float dn[64 * 9];
  const int tid = threadIdx.x;
  const int it = blockIdx.x >> 5, jt = blockIdx.x & 31;
  const int ibase = it * 64, jbase = jt * 64;
  const int w = tid >> 6, lane = tid & 63, lg = lane >> 4, ln = lane & 15;

  // stage this i-tile's denom rows (coalesced 512-float read)
  for (int e = tid; e < 512; e += 256) {
    const int il = e >> 3, h = e & 7;
    dn[il * 9 + h] = dnm[(ibase + il) * 8 + h];
  }
  __syncthreads();

  // per-lane copy of denom for its 4 i-rows (statically indexed in the h-unroll)
  float dnr[4][8];
#pragma unroll
  for (int q = 0; q < 4; ++q) {
    const int il = w * 16 + lg * 4 + q;
#pragma unroll
    for (int h = 0; h < 8; ++h) dnr[q][h] = dn[il * 9 + h];
  }

  const int irow = ibase + w * 16 + ln;
  float maxd[4][4], bestdn[4][4];
#pragma unroll
  for (int sj = 0; sj < 4; ++sj)
#pragma unroll
    for (int q = 0; q < 4; ++q) { maxd[sj][q] = -3.0e38f; bestdn[sj][q] = 0.0f; }

#pragma unroll
  for (int h = 0; h < 8; ++h) {
    const ushort_t* fh = fnb + h * (NROWS * 64);
    const bf16x8 a0 = ldb(fh + irow * 64 + lg * 8);
    const bf16x8 a1 = ldb(fh + irow * 64 + 32 + lg * 8);
#pragma unroll
    for (int sj = 0; sj < 4; ++sj) {
      const int jrow = jbase + sj * 16 + ln;
      const bf16x8 b0 = ldb(fh + jrow * 64 + lg * 8);
      const bf16x8 b1 = ldb(fh + jrow * 64 + 32 + lg * 8);
      f32x4 c = {0.0f, 0.0f, 0.0f, 0.0f};
      c = __builtin_amdgcn_mfma_f32_16x16x32_bf16(a0, b0, c, 0, 0, 0);
      c = __builtin_amdgcn_mfma_f32_16x16x32_bf16(a1, b1, c, 0, 0, 0);
#pragma unroll
      for (int q = 0; q < 4; ++q)
        if (c[q] > maxd[sj][q]) { maxd[sj][q] = c[q]; bestdn[sj][q] = dnr[q][h]; }  // first-max tiebreak
    }
  }

  u64 lbi[4];
#pragma unroll
  for (int q = 0; q < 4; ++q) lbi[q] = lbits[(ibase + w * 16 + lg * 4 + q) & (BLAB - 1)];
  float rs[4] = {0, 0, 0, 0}, rc[4] = {0, 0, 0, 0};
#pragma unroll
  for (int sj = 0; sj < 4; ++sj) {
    const int gj = jbase + sj * 16 + ln;
    const u64 lbj = lbits[gj & (BLAB - 1)];
#pragma unroll
    for (int q = 0; q < 4; ++q) {
      const int gi = ibase + w * 16 + lg * 4 + q;
      if (gi != gj && (lbi[q] & lbj)) {
        rs[q] += maxd[sj][q] * INVT - bestdn[sj][q];
        rc[q] += 1.0f;
      }
    }
  }
#pragma unroll
  for (int q = 0; q < 4; ++q) {
#pragma unroll
    for (int d = 1; d < 16; d <<= 1) {
      rs[q] += __shfl_xor(rs[q], d, 64);
      rc[q] += __shfl_xor(rc[q], d, 64);
    }
  }
  if (ln == 0) {
#pragma unroll
    for (int q = 0; q < 4; ++q) {
      const int row = ibase + w * 16 + lg * 4 + q;
      atomicAdd(&rowsum[row], rs[q]);
      atomicAdd(&rowcnt[row], rc[q]);
    }
  }
}

// final: mean over rows with cnt>0 of -(rowsum/cnt); empty -> 0
__global__ void k_final(const float* __restrict__ rowsum, const float* __restrict__ rowcnt,
                        float* __restrict__ out) {
  __shared__ float sdata[4][2];
  const int tid = threadIdx.x;
  float s = 0.0f, c = 0.0f;
  for (int i = tid; i < NROWS; i += 256) {
    const float cnt = rowcnt[i];
    if (cnt > 0.0f) { s -= rowsum[i] / cnt; c += 1.0f; }
  }
#pragma unroll
  for (int d = 32; d; d >>= 1) { s += __shfl_xor(s, d, 64); c += __shfl_xor(c, d, 64); }
  const int w = tid >> 6;
  if ((tid & 63) == 0) { sdata[w][0] = s; sdata[w][1] = c; }
  __syncthreads();
  if (tid == 0) {
    s = 0.0f; c = 0.0f;
#pragma unroll
    for (int w2 = 0; w2 < 4; ++w2) { s += sdata[w2][0]; c += sdata[w2][1]; }
    out[0] = (c > 0.0f) ? s / c : 0.0f;
  }
}

extern "C" void kernel_launch(void* const* d_in, const int* in_sizes, int n_in,
                              void* d_out, int out_size, void* d_ws, size_t ws_size,
                              hipStream_t stream) {
  const float* feat   = (const float*)d_in[0];
  const float* negs   = (const float*)d_in[1];
  const float* labels = (const float*)d_in[2];
  float* out = (float*)d_out;

  ushort_t* fnb = (ushort_t*)d_ws;              // (H,N,64) bf16 = 2 MB
  ushort_t* nnb = fnb + 8 * NROWS * 64;         // (H,M,64) bf16 = 4 MB
  float* m1p = (float*)(nnb + 8 * MROWS * 64);  // (N,128) each = 1 MB x 4
  float* S1p = m1p + NROWS * 128;
  float* m2p = S1p + NROWS * 128;
  float* S2p = m2p + NROWS * 128;
  float* rowsum = S2p + NROWS * 128;            // 2048
  float* rowcnt = rowsum + 2048;                // 2048
  u64*   lbits  = (u64*)(rowcnt + 2048);        // 1024
  float* dnm    = (float*)(lbits + 1024);       // (N,8) = 64 KB

  k_prep<<<3328, 256, 0, stream>>>(feat, negs, labels, fnb, nnb, lbits, rowsum);
  k_passA<<<1024, 256, 0, stream>>>(fnb, nnb, m1p, S1p, m2p, S2p);
  k_denom<<<64, 256, 0, stream>>>(m1p, S1p, m2p, S2p, dnm);
  k_passB<<<1024, 256, 0, stream>>>(fnb, dnm, lbits, rowsum, rowcnt);
  k_final<<<1, 256, 0, stream>>>(rowsum, rowcnt, out);
}